// Round 1
// baseline (1444.750 us; speedup 1.0000x reference)
//
#include <hip/hip_runtime.h>

typedef unsigned short u16;
typedef unsigned int u32;
typedef __attribute__((ext_vector_type(8))) short bf16x8;
typedef __attribute__((ext_vector_type(4))) float f32x4;

#define DEVI static __device__ __forceinline__

DEVI u16 f2b(float f){
  u32 x = __float_as_uint(f);
  return (u16)((x + 0x7fffu + ((x >> 16) & 1u)) >> 16);   // RNE bf16
}
DEVI float b2f(u16 u){ return __uint_as_float(((u32)u) << 16); }
DEVI float2 up2(u32 u){   // two packed bf16 -> two floats (low ushort = lower addr)
  return make_float2(__uint_as_float(u << 16), __uint_as_float(u & 0xffff0000u));
}
DEVI void gload16(const u16* g, u16* l){
  __builtin_amdgcn_global_load_lds((const __attribute__((address_space(1))) void*)g,
                                   (__attribute__((address_space(3))) void*)l,
                                   16, 0, 0);
}

// ---------------- fp32 -> bf16 convert (vectorized 4/thread) ----------------
__global__ void f2bf_k(const float* __restrict__ s, u16* __restrict__ d, int n4){
  int i = blockIdx.x * 256 + threadIdx.x;
  if (i >= n4) return;
  float4 f = ((const float4*)s)[i];
  u32 lo = (u32)f2b(f.x) | ((u32)f2b(f.y) << 16);
  u32 hi = (u32)f2b(f.z) | ((u32)f2b(f.w) << 16);
  ((uint2*)d)[i] = make_uint2(lo, hi);
}

// ---------------- MFMA bf16 GEMM:  C[M,N] = A[M,K] * W[N,K]^T ----------------
// 128x128 tile, BK=32, 256 thr = 4 waves (2x2), each wave 64x64 = 4x4 frags of 16x16x32.
// MODE 0: bf16 row-major (ld=N)   MODE 1: bf16 scatter h=n>>6,d=n&63 into (B,NH,S,128)
// MODE 2: bf16 scatter h=n>>7,d=n&127 into (B,NH,S,128)   MODE 3: fp32 row-major
template<int MODE>
__global__ __launch_bounds__(256, 2)
void gemm_bt(const u16* __restrict__ A, const u16* __restrict__ W,
             void* __restrict__ D, int N, int K){
  __shared__ u16 As[128 * 32];
  __shared__ u16 Bs[128 * 32];
  const int tid = threadIdx.x;
  const int wave = tid >> 6, lane = tid & 63;
  const int lr = lane & 15, lk = lane >> 4;
  const int m0 = blockIdx.y * 128, n0 = blockIdx.x * 128;
  const int wm = wave >> 1, wn = wave & 1;
  f32x4 acc[4][4] = {};

  const u16* a0 = A + (size_t)(m0 + (tid >> 2)) * K + (tid & 3) * 8;
  const u16* a1 = a0 + (size_t)64 * K;
  const u16* b0 = W + (size_t)(n0 + (tid >> 2)) * K + (tid & 3) * 8;
  const u16* b1 = b0 + (size_t)64 * K;
  u16* lA0 = As + wave * 512;  u16* lA1 = As + 2048 + wave * 512;
  u16* lB0 = Bs + wave * 512;  u16* lB1 = Bs + 2048 + wave * 512;

  for (int k0 = 0; k0 < K; k0 += 32){
    __syncthreads();
    gload16(a0 + k0, lA0);
    gload16(a1 + k0, lA1);
    gload16(b0 + k0, lB0);
    gload16(b1 + k0, lB1);
    asm volatile("s_waitcnt vmcnt(0)" ::: "memory");
    __syncthreads();
    bf16x8 af[4], bfr[4];
    #pragma unroll
    for (int i = 0; i < 4; i++)
      af[i] = *(const bf16x8*)(As + (wm * 64 + i * 16 + lr) * 32 + lk * 8);
    #pragma unroll
    for (int j = 0; j < 4; j++)
      bfr[j] = *(const bf16x8*)(Bs + (wn * 64 + j * 16 + lr) * 32 + lk * 8);
    #pragma unroll
    for (int i = 0; i < 4; i++)
      #pragma unroll
      for (int j = 0; j < 4; j++)
        acc[i][j] = __builtin_amdgcn_mfma_f32_16x16x32_bf16(af[i], bfr[j], acc[i][j], 0, 0, 0);
  }

  const int rb = (lane >> 4) * 4, cl = lane & 15;
  #pragma unroll
  for (int i = 0; i < 4; i++){
    #pragma unroll
    for (int j = 0; j < 4; j++){
      #pragma unroll
      for (int r = 0; r < 4; r++){
        int m = m0 + wm * 64 + i * 16 + rb + r;
        int n = n0 + wn * 64 + j * 16 + cl;
        float v = acc[i][j][r];
        if (MODE == 0){
          ((u16*)D)[(size_t)m * N + n] = f2b(v);
        } else if (MODE == 3){
          ((float*)D)[(size_t)m * N + n] = v;
        } else if (MODE == 1){
          int h = n >> 6, d = n & 63;
          ((u16*)D)[(((size_t)(m >> 11) * 16 + h) * 2048 + (m & 2047)) * 128 + d] = f2b(v);
        } else {
          int h = n >> 7, d = n & 127;
          ((u16*)D)[(((size_t)(m >> 11) * 16 + h) * 2048 + (m & 2047)) * 128 + d] = f2b(v);
        }
      }
    }
  }
}

// ---------------- RoPE: rotate q_r/k_r halves into q/k dims [64,128) ----------------
__global__ void rope_k(const u16* __restrict__ qrp, const u16* __restrict__ krp,
                       u16* __restrict__ Qb, u16* __restrict__ Kb){
  int idx = blockIdx.x * 256 + threadIdx.x;         // 2*2048*16*32 = 2^21
  if (idx >= (1 << 21)) return;
  int j = idx & 31, h = (idx >> 5) & 15, s = (idx >> 9) & 2047, b = (idx >> 20) & 1;
  // inv_freq[j] = 10000^(-j/32) ; angle = s * inv_freq (fp32, matches ref)
  float inv = exp2f((float)j * (-13.287712379549449f / 32.0f));
  float ang = (float)s * inv;
  float sn = sinf(ang), cs = cosf(ang);
  size_t so = ((size_t)(b * 2048 + s)) * 1024 + h * 64 + j;
  size_t dd = (((size_t)(b * 16 + h)) * 2048 + s) * 128;
  {
    float x1 = b2f(qrp[so]), x2 = b2f(qrp[so + 32]);
    Qb[dd + 64 + j] = f2b(x1 * cs - x2 * sn);
    Qb[dd + 96 + j] = f2b(x1 * sn + x2 * cs);
  }
  {
    float x1 = b2f(krp[so]), x2 = b2f(krp[so + 32]);
    Kb[dd + 64 + j] = f2b(x1 * cs - x2 * sn);
    Kb[dd + 96 + j] = f2b(x1 * sn + x2 * cs);
  }
}

// ---------------- flash attention (fp32 VALU this round) ----------------
// grid (S/64, B*NH); 256 thr as 16x16; thread (ty,tx): score rows ty*4+i, cols tx*4+j;
// PV: same rows, d = tx*8+jj. Online softmax, causal tile skipping.
__global__ __launch_bounds__(256, 2)
void flash_attn(const u16* __restrict__ Q, const u16* __restrict__ K,
                const u16* __restrict__ V, u16* __restrict__ Y){
  __shared__ u16 q_s[64 * 132];
  __shared__ u16 k_s[64 * 132];
  __shared__ u16 v_s[64 * 132];
  __shared__ u16 p_s[64 * 68];
  const int tid = threadIdx.x;
  const int tx = tid & 15, ty = tid >> 4;
  const int qt = blockIdx.x, bh = blockIdx.y;
  const int b = bh >> 4, h = bh & 15;
  const size_t base = (size_t)bh * 2048 * 128;
  const u16* Qb = Q + base + (size_t)qt * 64 * 128;
  const u16* Kb = K + base;
  const u16* Vb = V + base;

  { // stage Q tile once
    int rw = tid >> 4, c8 = (tid & 15) * 8;
    #pragma unroll
    for (int rr = 0; rr < 4; rr++){
      int r = rr * 16 + rw;
      uint4 w = *(const uint4*)(Qb + (size_t)r * 128 + c8);
      *(uint2*)(q_s + r * 132 + c8)     = make_uint2(w.x, w.y);
      *(uint2*)(q_s + r * 132 + c8 + 4) = make_uint2(w.z, w.w);
    }
  }

  float m_prev[4], l_sum[4], o_acc[4][8];
  #pragma unroll
  for (int i = 0; i < 4; i++){
    m_prev[i] = -1e30f; l_sum[i] = 0.f;
    #pragma unroll
    for (int jj = 0; jj < 8; jj++) o_acc[i][jj] = 0.f;
  }

  for (int kt = 0; kt <= qt; ++kt){
    __syncthreads();                       // prev PV done with v_s/p_s, scores with k_s
    { // stage K,V tiles
      int rw = tid >> 4, c8 = (tid & 15) * 8;
      #pragma unroll
      for (int rr = 0; rr < 4; rr++){
        int r = rr * 16 + rw;
        uint4 wk = *(const uint4*)(Kb + (size_t)(kt * 64 + r) * 128 + c8);
        *(uint2*)(k_s + r * 132 + c8)     = make_uint2(wk.x, wk.y);
        *(uint2*)(k_s + r * 132 + c8 + 4) = make_uint2(wk.z, wk.w);
        uint4 wv = *(const uint4*)(Vb + (size_t)(kt * 64 + r) * 128 + c8);
        *(uint2*)(v_s + r * 132 + c8)     = make_uint2(wv.x, wv.y);
        *(uint2*)(v_s + r * 132 + c8 + 4) = make_uint2(wv.z, wv.w);
      }
    }
    __syncthreads();

    // ---- scores S = Q K^T (64x64), 4x4 per thread ----
    float sc[4][4] = {};
    for (int d0 = 0; d0 < 128; d0 += 4){
      float qv[4][4], kv[4][4];
      #pragma unroll
      for (int i = 0; i < 4; i++){
        uint2 u = *(const uint2*)(q_s + (ty * 4 + i) * 132 + d0);
        float2 f0 = up2(u.x), f1 = up2(u.y);
        qv[i][0] = f0.x; qv[i][1] = f0.y; qv[i][2] = f1.x; qv[i][3] = f1.y;
      }
      #pragma unroll
      for (int j = 0; j < 4; j++){
        uint2 u = *(const uint2*)(k_s + (tx * 4 + j) * 132 + d0);
        float2 f0 = up2(u.x), f1 = up2(u.y);
        kv[j][0] = f0.x; kv[j][1] = f0.y; kv[j][2] = f1.x; kv[j][3] = f1.y;
      }
      #pragma unroll
      for (int i = 0; i < 4; i++)
        #pragma unroll
        for (int j = 0; j < 4; j++)
          sc[i][j] += qv[i][0] * kv[j][0] + qv[i][1] * kv[j][1]
                    + qv[i][2] * kv[j][2] + qv[i][3] * kv[j][3];
    }

    // ---- causal mask + online softmax (row reduce over tx bits) ----
    const float scale = 0.08838834764831845f;  // 1/sqrt(128)
    #pragma unroll
    for (int i = 0; i < 4; i++){
      int qrow = qt * 64 + ty * 4 + i;
      float rmax = -1e30f;
      #pragma unroll
      for (int j = 0; j < 4; j++){
        int kc = kt * 64 + tx * 4 + j;
        sc[i][j] = (kc <= qrow) ? sc[i][j] * scale : -1e30f;
        rmax = fmaxf(rmax, sc[i][j]);
      }
      #pragma unroll
      for (int off = 1; off < 16; off <<= 1) rmax = fmaxf(rmax, __shfl_xor(rmax, off));
      float mnew = fmaxf(m_prev[i], rmax);
      float alpha = __expf(m_prev[i] - mnew);
      m_prev[i] = mnew;
      float p0 = __expf(sc[i][0] - mnew), p1 = __expf(sc[i][1] - mnew);
      float p2 = __expf(sc[i][2] - mnew), p3 = __expf(sc[i][3] - mnew);
      float rsum = p0 + p1 + p2 + p3;
      u32 pk0 = (u32)f2b(p0) | ((u32)f2b(p1) << 16);
      u32 pk1 = (u32)f2b(p2) | ((u32)f2b(p3) << 16);
      #pragma unroll
      for (int off = 1; off < 16; off <<= 1) rsum += __shfl_xor(rsum, off);
      l_sum[i] = l_sum[i] * alpha + rsum;
      #pragma unroll
      for (int jj = 0; jj < 8; jj++) o_acc[i][jj] *= alpha;
      *(uint2*)(p_s + (ty * 4 + i) * 68 + tx * 4) = make_uint2(pk0, pk1);
    }
    __syncthreads();                        // p_s visible

    // ---- PV: o[r][d] += sum_c p[r][c] * v[c][d] ----
    for (int c = 0; c < 64; c++){
      const u16* vp = v_s + c * 132 + tx * 8;
      uint2 va = *(const uint2*)vp, vb2 = *(const uint2*)(vp + 4);
      float vv[8]; float2 f;
      f = up2(va.x);  vv[0] = f.x; vv[1] = f.y;
      f = up2(va.y);  vv[2] = f.x; vv[3] = f.y;
      f = up2(vb2.x); vv[4] = f.x; vv[5] = f.y;
      f = up2(vb2.y); vv[6] = f.x; vv[7] = f.y;
      #pragma unroll
      for (int i = 0; i < 4; i++){
        float p = b2f(p_s[(ty * 4 + i) * 68 + c]);
        #pragma unroll
        for (int jj = 0; jj < 8; jj++) o_acc[i][jj] = fmaf(p, vv[jj], o_acc[i][jj]);
      }
    }
  }

  // ---- finalize: y[t, h*128 + d] bf16, token-major ----
  #pragma unroll
  for (int i = 0; i < 4; i++){
    float inv = 1.0f / l_sum[i];
    u32 u0 = (u32)f2b(o_acc[i][0] * inv) | ((u32)f2b(o_acc[i][1] * inv) << 16);
    u32 u1 = (u32)f2b(o_acc[i][2] * inv) | ((u32)f2b(o_acc[i][3] * inv) << 16);
    u32 u2 = (u32)f2b(o_acc[i][4] * inv) | ((u32)f2b(o_acc[i][5] * inv) << 16);
    u32 u3 = (u32)f2b(o_acc[i][6] * inv) | ((u32)f2b(o_acc[i][7] * inv) << 16);
    size_t off = ((size_t)b * 2048 + qt * 64 + ty * 4 + i) * 2048 + h * 128 + tx * 8;
    *(uint4*)(Y + off) = make_uint4(u0, u1, u2, u3);
  }
}

// ---------------------------------------------------------------------------
extern "C" void kernel_launch(void* const* d_in, const int* in_sizes, int n_in,
                              void* d_out, int out_size, void* d_ws, size_t ws_size,
                              hipStream_t stream){
  // sizes: x 8388608, W_kv_d 524288, W_q_d 524288, W_k_u 262144, W_q_u 262144,
  //        W_v_u 524288, W_rope_k 2097152, W_rope_q 262144, W_o 4194304
  u16* p = (u16*)d_ws;
  auto alloc = [&](size_t n){ u16* r = p; p += n; return r; };
  u16* xb   = alloc(8388608);
  u16* wkvb = alloc(524288);
  u16* wqdb = alloc(524288);
  u16* wkub = alloc(262144);
  u16* wqub = alloc(262144);
  u16* wvub = alloc(524288);
  u16* wrkb = alloc(2097152);
  u16* wrqb = alloc(262144);
  u16* wob  = alloc(4194304);
  u16* kvdb = alloc(1048576);   // (4096,256) bf16
  u16* qdb  = alloc(1048576);
  u16* krp  = alloc(4194304);   // (4096,1024) pre-rope
  u16* qrp  = alloc(4194304);
  u16* qbuf = alloc(8388608);   // (B,NH,S,128) bf16
  u16* kbuf = alloc(8388608);
  u16* vbuf = alloc(8388608);
  u16* ybuf = alloc(8388608);   // (4096,2048) bf16
  // total ~116.5 MiB of ws

  auto cvt = [&](const void* s, u16* d, int n){
    int n4 = n / 4;
    f2bf_k<<<(n4 + 255) / 256, 256, 0, stream>>>((const float*)s, d, n4);
  };
  cvt(d_in[0], xb,   8388608);
  cvt(d_in[1], wkvb, 524288);
  cvt(d_in[2], wqdb, 524288);
  cvt(d_in[3], wkub, 262144);
  cvt(d_in[4], wqub, 262144);
  cvt(d_in[5], wvub, 524288);
  cvt(d_in[6], wrkb, 2097152);
  cvt(d_in[7], wrqb, 262144);
  cvt(d_in[8], wob,  4194304);

  dim3 blk(256);
  // latent projections (K=2048)
  gemm_bt<0><<<dim3(2, 32),  blk, 0, stream>>>(xb,   wkvb, kvdb, 256,  2048);
  gemm_bt<0><<<dim3(2, 32),  blk, 0, stream>>>(xb,   wqdb, qdb,  256,  2048);
  gemm_bt<0><<<dim3(8, 32),  blk, 0, stream>>>(xb,   wrkb, krp,  1024, 2048);
  // up-projections (K=256)
  gemm_bt<0><<<dim3(8, 32),  blk, 0, stream>>>(qdb,  wrqb, qrp,  1024, 256);
  gemm_bt<1><<<dim3(8, 32),  blk, 0, stream>>>(kvdb, wkub, kbuf, 1024, 256);
  gemm_bt<1><<<dim3(8, 32),  blk, 0, stream>>>(qdb,  wqub, qbuf, 1024, 256);
  gemm_bt<2><<<dim3(16, 32), blk, 0, stream>>>(kvdb, wvub, vbuf, 2048, 256);
  // rope into q/k dims [64,128)
  rope_k<<<(1 << 21) / 256, 256, 0, stream>>>(qrp, krp, qbuf, kbuf);
  // attention
  flash_attn<<<dim3(32, 32), blk, 0, stream>>>(qbuf, kbuf, vbuf, ybuf);
  // output projection (fp32 out)
  gemm_bt<3><<<dim3(16, 32), blk, 0, stream>>>(ybuf, wob, d_out, 2048, 2048);
}

// Round 2
// 399.786 us; speedup vs baseline: 3.6138x; 3.6138x over previous
//
#include <hip/hip_runtime.h>

typedef unsigned short u16;
typedef unsigned int u32;
typedef __attribute__((ext_vector_type(8))) short bf16x8;
typedef __attribute__((ext_vector_type(4))) float f32x4;

#define DEVI static __device__ __forceinline__

DEVI u16 f2b(float f){
  u32 x = __float_as_uint(f);
  return (u16)((x + 0x7fffu + ((x >> 16) & 1u)) >> 16);   // RNE bf16
}
DEVI float b2f(u16 u){ return __uint_as_float(((u32)u) << 16); }
DEVI void gload16(const u16* g, u16* l){
  __builtin_amdgcn_global_load_lds((const __attribute__((address_space(1))) void*)g,
                                   (__attribute__((address_space(3))) void*)l,
                                   16, 0, 0);
}

// ---------------- fp32 -> bf16 convert (vectorized 4/thread) ----------------
__global__ void f2bf_k(const float* __restrict__ s, u16* __restrict__ d, int n4){
  int i = blockIdx.x * 256 + threadIdx.x;
  if (i >= n4) return;
  float4 f = ((const float4*)s)[i];
  u32 lo = (u32)f2b(f.x) | ((u32)f2b(f.y) << 16);
  u32 hi = (u32)f2b(f.z) | ((u32)f2b(f.w) << 16);
  ((uint2*)d)[i] = make_uint2(lo, hi);
}

// ---------------- MFMA bf16 GEMM:  C[M,N] = A[M,K] * W[N,K]^T ----------------
// 128x128 tile, BK=32, 256 thr = 4 waves (2x2), each wave 64x64 = 4x4 frags.
// MODE 0: bf16 row-major (ld=N)       MODE 1: bf16 scatter h=n>>6,d=n&63 -> (B,NH,S,128)
// MODE 3: fp32 row-major              MODE 4: bf16 V^T scatter -> (B,NH,128,S), packed x4
template<int MODE>
__global__ __launch_bounds__(256, 2)
void gemm_bt(const u16* __restrict__ A, const u16* __restrict__ W,
             void* __restrict__ D, int N, int K){
  __shared__ u16 As[128 * 32];
  __shared__ u16 Bs[128 * 32];
  const int tid = threadIdx.x;
  const int wave = tid >> 6, lane = tid & 63;
  const int lr = lane & 15, lk = lane >> 4;
  const int m0 = blockIdx.y * 128, n0 = blockIdx.x * 128;
  const int wm = wave >> 1, wn = wave & 1;
  f32x4 acc[4][4] = {};

  const u16* a0 = A + (size_t)(m0 + (tid >> 2)) * K + (tid & 3) * 8;
  const u16* a1 = a0 + (size_t)64 * K;
  const u16* b0 = W + (size_t)(n0 + (tid >> 2)) * K + (tid & 3) * 8;
  const u16* b1 = b0 + (size_t)64 * K;
  u16* lA0 = As + wave * 512;  u16* lA1 = As + 2048 + wave * 512;
  u16* lB0 = Bs + wave * 512;  u16* lB1 = Bs + 2048 + wave * 512;

  for (int k0 = 0; k0 < K; k0 += 32){
    __syncthreads();
    gload16(a0 + k0, lA0);
    gload16(a1 + k0, lA1);
    gload16(b0 + k0, lB0);
    gload16(b1 + k0, lB1);
    asm volatile("s_waitcnt vmcnt(0)" ::: "memory");
    __syncthreads();
    bf16x8 af[4], bfr[4];
    #pragma unroll
    for (int i = 0; i < 4; i++)
      af[i] = *(const bf16x8*)(As + (wm * 64 + i * 16 + lr) * 32 + lk * 8);
    #pragma unroll
    for (int j = 0; j < 4; j++)
      bfr[j] = *(const bf16x8*)(Bs + (wn * 64 + j * 16 + lr) * 32 + lk * 8);
    #pragma unroll
    for (int i = 0; i < 4; i++)
      #pragma unroll
      for (int j = 0; j < 4; j++)
        acc[i][j] = __builtin_amdgcn_mfma_f32_16x16x32_bf16(af[i], bfr[j], acc[i][j], 0, 0, 0);
  }

  const int rb = (lane >> 4) * 4, cl = lane & 15;
  #pragma unroll
  for (int i = 0; i < 4; i++){
    #pragma unroll
    for (int j = 0; j < 4; j++){
      const int mb = m0 + wm * 64 + i * 16 + rb;
      const int n  = n0 + wn * 64 + j * 16 + cl;
      if (MODE == 4){
        int h = n >> 7, d = n & 127, b = mb >> 11, s = mb & 2047;
        u32 lo = (u32)f2b(acc[i][j][0]) | ((u32)f2b(acc[i][j][1]) << 16);
        u32 hi = (u32)f2b(acc[i][j][2]) | ((u32)f2b(acc[i][j][3]) << 16);
        *(uint2*)((u16*)D + (((size_t)(b * 16 + h) * 128 + d) * 2048 + s)) = make_uint2(lo, hi);
      } else {
        #pragma unroll
        for (int r = 0; r < 4; r++){
          int m = mb + r;
          float v = acc[i][j][r];
          if (MODE == 0){
            ((u16*)D)[(size_t)m * N + n] = f2b(v);
          } else if (MODE == 3){
            ((float*)D)[(size_t)m * N + n] = v;
          } else {  // MODE 1
            int h = n >> 6, d = n & 63;
            ((u16*)D)[(((size_t)(m >> 11) * 16 + h) * 2048 + (m & 2047)) * 128 + d] = f2b(v);
          }
        }
      }
    }
  }
}

// ---------------- RoPE: rotate q_r/k_r halves into q/k dims [64,128) ----------------
__global__ void rope_k(const u16* __restrict__ qrp, const u16* __restrict__ krp,
                       u16* __restrict__ Qb, u16* __restrict__ Kb){
  int idx = blockIdx.x * 256 + threadIdx.x;         // 2*2048*16*32 = 2^21
  if (idx >= (1 << 21)) return;
  int j = idx & 31, h = (idx >> 5) & 15, s = (idx >> 9) & 2047, b = (idx >> 20) & 1;
  float inv = exp2f((float)j * (-13.287712379549449f / 32.0f));
  float ang = (float)s * inv;
  float sn = sinf(ang), cs = cosf(ang);
  size_t so = ((size_t)(b * 2048 + s)) * 1024 + h * 64 + j;
  size_t dd = (((size_t)(b * 16 + h)) * 2048 + s) * 128;
  {
    float x1 = b2f(qrp[so]), x2 = b2f(qrp[so + 32]);
    Qb[dd + 64 + j] = f2b(x1 * cs - x2 * sn);
    Qb[dd + 96 + j] = f2b(x1 * sn + x2 * cs);
  }
  {
    float x1 = b2f(krp[so]), x2 = b2f(krp[so + 32]);
    Kb[dd + 64 + j] = f2b(x1 * cs - x2 * sn);
    Kb[dd + 96 + j] = f2b(x1 * sn + x2 * cs);
  }
}

// ---------------- MFMA flash attention ----------------
// grid (16, B*NH); 4 waves, each owns 32 q-rows of a 128-row Q tile. K/V tiles 64.
// K in (B,NH,S,128); V pre-transposed (B,NH,128,S). LDS XOR-swizzle (row&7)<<4.
__global__ __launch_bounds__(256, 2)
void flash_mfma(const u16* __restrict__ Q, const u16* __restrict__ K,
                const u16* __restrict__ VT, u16* __restrict__ Y){
  __shared__ u16 smem[8192 + 8192 + 8192];   // k_s | v_s | p_s  (48 KiB)
  u16* k_s = smem;            // 64 rows x 128 (256B rows, swizzled)
  u16* v_s = smem + 8192;     // 128 rows x 64 (128B rows, swizzled)
  u16* p_s = smem + 16384;    // 4 waves x 32 x 64 (swizzled)
  const int tid = threadIdx.x;
  const int w = tid >> 6, l = tid & 63;
  const int lr = l & 15, hk = l >> 4, l7 = l & 7;
  const int qt = 15 - blockIdx.x;             // heavy tiles dispatched first
  const int bh = blockIdx.y;
  const int b = bh >> 4, h = bh & 15;
  const size_t base = (size_t)bh * 2048 * 128;
  const u16* Qb = Q + base;
  const u16* Kb = K + base;
  const u16* Vb = VT + base;
  const int q0 = qt * 128 + w * 32;
  u16* myp = p_s + w * 2048;

  // Q fragments in registers: qa[mi][ks] = Q[q0+mi*16+lr][ks*32 + hk*8 ..+8]
  bf16x8 qa[2][4];
  #pragma unroll
  for (int mi = 0; mi < 2; mi++)
    #pragma unroll
    for (int ks = 0; ks < 4; ks++)
      qa[mi][ks] = *(const bf16x8*)(Qb + (size_t)(q0 + mi * 16 + lr) * 128 + ks * 32 + hk * 8);

  f32x4 o[2][8] = {};
  float mrow[2][4], lsum[2][4];
  #pragma unroll
  for (int mi = 0; mi < 2; mi++)
    #pragma unroll
    for (int r = 0; r < 4; r++){ mrow[mi][r] = -1e30f; lsum[mi][r] = 0.f; }

  const int nkt = 2 * qt + 2;
  for (int kt = 0; kt < nkt; ++kt){
    __syncthreads();
    // stage K tile: linear LDS dest, inverse-swizzled global source
    #pragma unroll
    for (int it = 0; it < 4; ++it){
      int row = w * 16 + it * 4 + hk;
      const u16* src = Kb + (size_t)(kt * 64 + row) * 128 + ((lr << 3) ^ ((row & 7) << 3));
      gload16(src, k_s + w * 2048 + it * 512);
    }
    // stage V^T tile
    #pragma unroll
    for (int it = 0; it < 4; ++it){
      int chunk = w * 4 + it;
      int d = chunk * 8 + (l >> 3);
      const u16* src = Vb + (size_t)d * 2048 + kt * 64 + (((l7) ^ (l >> 3)) << 3);
      gload16(src, v_s + chunk * 512);
    }
    asm volatile("s_waitcnt vmcnt(0)" ::: "memory");
    __syncthreads();

    if (kt * 64 <= q0 + 31){
      // ---- S = Q K^T ----
      f32x4 sc[2][4] = {};
      #pragma unroll
      for (int ks = 0; ks < 4; ++ks){
        bf16x8 kb[4];
        #pragma unroll
        for (int nj = 0; nj < 4; ++nj)
          kb[nj] = *(const bf16x8*)(k_s + (nj * 16 + lr) * 128 + (((ks * 64 + hk * 16) ^ (l7 << 4)) >> 1));
        #pragma unroll
        for (int mi = 0; mi < 2; ++mi)
          #pragma unroll
          for (int nj = 0; nj < 4; ++nj)
            sc[mi][nj] = __builtin_amdgcn_mfma_f32_16x16x32_bf16(qa[mi][ks], kb[nj], sc[mi][nj], 0, 0, 0);
      }
      // ---- causal mask + online softmax (C layout: row=hk*4+r, col=lr) ----
      const float scale = 0.08838834764831845f;   // 1/sqrt(128)
      #pragma unroll
      for (int mi = 0; mi < 2; ++mi){
        #pragma unroll
        for (int r = 0; r < 4; ++r){
          int qrow = q0 + mi * 16 + hk * 4 + r;
          float pv[4], rmax = -1e30f;
          #pragma unroll
          for (int nj = 0; nj < 4; ++nj){
            int kc = kt * 64 + nj * 16 + lr;
            float s = (kc <= qrow) ? sc[mi][nj][r] * scale : -1e30f;
            pv[nj] = s; rmax = fmaxf(rmax, s);
          }
          #pragma unroll
          for (int off = 1; off < 16; off <<= 1) rmax = fmaxf(rmax, __shfl_xor(rmax, off));
          float mnew = fmaxf(mrow[mi][r], rmax);
          float alpha = __expf(mrow[mi][r] - mnew);
          mrow[mi][r] = mnew;
          int ql = mi * 16 + hk * 4 + r;
          int swz = (ql & 7) << 3;
          float rsum = 0.f;
          #pragma unroll
          for (int nj = 0; nj < 4; ++nj){
            float p = __expf(pv[nj] - mnew);
            rsum += p;
            myp[ql * 64 + ((nj * 16 + lr) ^ swz)] = f2b(p);
          }
          #pragma unroll
          for (int off = 1; off < 16; off <<= 1) rsum += __shfl_xor(rsum, off);
          lsum[mi][r] = lsum[mi][r] * alpha + rsum;
          #pragma unroll
          for (int dj = 0; dj < 8; ++dj) o[mi][dj][r] *= alpha;
        }
      }
      asm volatile("s_waitcnt lgkmcnt(0)" ::: "memory");   // P writes visible to own reads
      // ---- O += P V ----
      #pragma unroll
      for (int kk = 0; kk < 2; ++kk){
        bf16x8 pa[2], vb[8];
        #pragma unroll
        for (int mi = 0; mi < 2; ++mi)
          pa[mi] = *(const bf16x8*)(myp + (mi * 16 + lr) * 64 + ((kk * 32 + hk * 8) ^ (l7 << 3)));
        #pragma unroll
        for (int dj = 0; dj < 8; ++dj)
          vb[dj] = *(const bf16x8*)(v_s + (dj * 16 + lr) * 64 + (((kk * 64 + hk * 16) ^ (l7 << 4)) >> 1));
        #pragma unroll
        for (int mi = 0; mi < 2; ++mi)
          #pragma unroll
          for (int dj = 0; dj < 8; ++dj)
            o[mi][dj] = __builtin_amdgcn_mfma_f32_16x16x32_bf16(pa[mi], vb[dj], o[mi][dj], 0, 0, 0);
      }
    }
  }

  // ---- epilogue: normalize, transpose via LDS, coalesced store ----
  __syncthreads();                      // everyone done with k_s/v_s
  u16* scr = smem + w * 4096;           // 32 x 128 per wave
  #pragma unroll
  for (int mi = 0; mi < 2; ++mi){
    float inv[4];
    #pragma unroll
    for (int r = 0; r < 4; ++r) inv[r] = 1.0f / lsum[mi][r];
    #pragma unroll
    for (int dj = 0; dj < 8; ++dj)
      #pragma unroll
      for (int r = 0; r < 4; ++r)
        scr[(mi * 16 + hk * 4 + r) * 128 + dj * 16 + lr] = f2b(o[mi][dj][r] * inv[r]);
  }
  asm volatile("s_waitcnt lgkmcnt(0)" ::: "memory");
  #pragma unroll
  for (int rr = 0; rr < 8; ++rr){
    int row = rr * 4 + hk;
    uint4 v = *(const uint4*)(scr + row * 128 + lr * 8);
    *(uint4*)(Y + ((size_t)(b * 2048 + qt * 128 + w * 32 + row)) * 2048 + h * 128 + lr * 8) = v;
  }
}

// ---------------------------------------------------------------------------
extern "C" void kernel_launch(void* const* d_in, const int* in_sizes, int n_in,
                              void* d_out, int out_size, void* d_ws, size_t ws_size,
                              hipStream_t stream){
  u16* p = (u16*)d_ws;
  auto alloc = [&](size_t n){ u16* r = p; p += n; return r; };
  u16* xb   = alloc(8388608);
  u16* wkvb = alloc(524288);
  u16* wqdb = alloc(524288);
  u16* wkub = alloc(262144);
  u16* wqub = alloc(262144);
  u16* wvub = alloc(524288);
  u16* wrkb = alloc(2097152);
  u16* wrqb = alloc(262144);
  u16* wob  = alloc(4194304);
  u16* kvdb = alloc(1048576);   // (4096,256) bf16
  u16* qdb  = alloc(1048576);
  u16* krp  = alloc(4194304);   // (4096,1024) pre-rope
  u16* qrp  = alloc(4194304);
  u16* qbuf = alloc(8388608);   // (B,NH,S,128) bf16
  u16* kbuf = alloc(8388608);
  u16* vt   = alloc(8388608);   // (B,NH,128,S) bf16  — V transposed
  u16* ybuf = alloc(8388608);   // (4096,2048) bf16

  auto cvt = [&](const void* s, u16* d, int n){
    int n4 = n / 4;
    f2bf_k<<<(n4 + 255) / 256, 256, 0, stream>>>((const float*)s, d, n4);
  };
  cvt(d_in[0], xb,   8388608);
  cvt(d_in[1], wkvb, 524288);
  cvt(d_in[2], wqdb, 524288);
  cvt(d_in[3], wkub, 262144);
  cvt(d_in[4], wqub, 262144);
  cvt(d_in[5], wvub, 524288);
  cvt(d_in[6], wrkb, 2097152);
  cvt(d_in[7], wrqb, 262144);
  cvt(d_in[8], wob,  4194304);

  dim3 blk(256);
  // latent projections (K=2048)
  gemm_bt<0><<<dim3(2, 32),  blk, 0, stream>>>(xb,   wkvb, kvdb, 256,  2048);
  gemm_bt<0><<<dim3(2, 32),  blk, 0, stream>>>(xb,   wqdb, qdb,  256,  2048);
  gemm_bt<0><<<dim3(8, 32),  blk, 0, stream>>>(xb,   wrkb, krp,  1024, 2048);
  // up-projections (K=256)
  gemm_bt<0><<<dim3(8, 32),  blk, 0, stream>>>(qdb,  wrqb, qrp,  1024, 256);
  gemm_bt<1><<<dim3(8, 32),  blk, 0, stream>>>(kvdb, wkub, kbuf, 1024, 256);
  gemm_bt<1><<<dim3(8, 32),  blk, 0, stream>>>(qdb,  wqub, qbuf, 1024, 256);
  gemm_bt<4><<<dim3(16, 32), blk, 0, stream>>>(kvdb, wvub, vt,   2048, 256);
  // rope into q/k dims [64,128)
  rope_k<<<(1 << 21) / 256, 256, 0, stream>>>(qrp, krp, qbuf, kbuf);
  // attention (MFMA)
  flash_mfma<<<dim3(16, 32), blk, 0, stream>>>(qbuf, kbuf, vt, ybuf);
  // output projection (fp32 out)
  gemm_bt<3><<<dim3(16, 32), blk, 0, stream>>>(ybuf, wob, d_out, 2048, 2048);
}

// Round 3
// 301.842 us; speedup vs baseline: 4.7864x; 1.3245x over previous
//
#include <hip/hip_runtime.h>

typedef unsigned short u16;
typedef unsigned int u32;
typedef __attribute__((ext_vector_type(8))) short bf16x8;
typedef __attribute__((ext_vector_type(4))) float f32x4;

#define DEVI static __device__ __forceinline__

DEVI u16 f2b(float f){
  u32 x = __float_as_uint(f);
  return (u16)((x + 0x7fffu + ((x >> 16) & 1u)) >> 16);   // RNE bf16
}
DEVI float b2f(u16 u){ return __uint_as_float(((u32)u) << 16); }
DEVI void gload16(const u16* g, u16* l){
  __builtin_amdgcn_global_load_lds((const __attribute__((address_space(1))) void*)g,
                                   (__attribute__((address_space(3))) void*)l,
                                   16, 0, 0);
}

// ---------------- fp32 -> bf16 convert: x (one launch) ----------------
__global__ void f2bf_k(const float* __restrict__ s, u16* __restrict__ d, int n4){
  int i = blockIdx.x * 256 + threadIdx.x;
  if (i >= n4) return;
  float4 f = ((const float4*)s)[i];
  u32 lo = (u32)f2b(f.x) | ((u32)f2b(f.y) << 16);
  u32 hi = (u32)f2b(f.z) | ((u32)f2b(f.w) << 16);
  ((uint2*)d)[i] = make_uint2(lo, hi);
}

// ---------------- all 8 weights -> one contiguous bf16 region ----------------
struct WSrc { const float* s[8]; };
__global__ void wcvt_k(WSrc ws, u16* __restrict__ d){
  int i = blockIdx.x * 256 + threadIdx.x;        // float4 index, total 2162688
  if (i >= 2162688) return;
  const float4* s; int lo;
  if      (i <  131072){ s = (const float4*)ws.s[0]; lo = 0;       }
  else if (i <  262144){ s = (const float4*)ws.s[1]; lo = 131072;  }
  else if (i <  786432){ s = (const float4*)ws.s[2]; lo = 262144;  }
  else if (i <  851968){ s = (const float4*)ws.s[3]; lo = 786432;  }
  else if (i <  917504){ s = (const float4*)ws.s[4]; lo = 851968;  }
  else if (i <  983040){ s = (const float4*)ws.s[5]; lo = 917504;  }
  else if (i < 1114112){ s = (const float4*)ws.s[6]; lo = 983040;  }
  else                 { s = (const float4*)ws.s[7]; lo = 1114112; }
  float4 f = s[i - lo];
  u32 a = (u32)f2b(f.x) | ((u32)f2b(f.y) << 16);
  u32 b = (u32)f2b(f.z) | ((u32)f2b(f.w) << 16);
  ((uint2*)d)[i] = make_uint2(a, b);
}

// ---------------- MFMA bf16 GEMM:  C[M,N] = A[M,K] * W[N,K]^T ----------------
// 128x128 tile, BK=32, 256 thr = 4 waves (2x2), each wave 64x64 = 4x4 frags.
// MODE 0: bf16 row-major ld=N into D          MODE 3: fp32 row-major into D
// MODE 6: n<1024 -> D2 row-major ld=1024; else scatter h=(n-1024)>>6,d&63 -> D (B,NH,S,128)
// MODE 7: n<1024 -> scatter h=n>>6,d&63 -> D; else n'=n-1024 V^T packed -> D2 (B,NH,128,S)
template<int MODE>
__global__ __launch_bounds__(256, 2)
void gemm_bt(const u16* __restrict__ A, int lda, const u16* __restrict__ W,
             void* __restrict__ D, void* __restrict__ D2, int N, int K){
  __shared__ u16 As[128 * 32];
  __shared__ u16 Bs[128 * 32];
  const int tid = threadIdx.x;
  const int wave = tid >> 6, lane = tid & 63;
  const int lr = lane & 15, lk = lane >> 4;
  const int m0 = blockIdx.y * 128, n0 = blockIdx.x * 128;
  const int wm = wave >> 1, wn = wave & 1;
  f32x4 acc[4][4] = {};

  const u16* a0 = A + (size_t)(m0 + (tid >> 2)) * lda + (tid & 3) * 8;
  const u16* a1 = a0 + (size_t)64 * lda;
  const u16* b0 = W + (size_t)(n0 + (tid >> 2)) * K + (tid & 3) * 8;
  const u16* b1 = b0 + (size_t)64 * K;
  u16* lA0 = As + wave * 512;  u16* lA1 = As + 2048 + wave * 512;
  u16* lB0 = Bs + wave * 512;  u16* lB1 = Bs + 2048 + wave * 512;

  for (int k0 = 0; k0 < K; k0 += 32){
    __syncthreads();
    gload16(a0 + k0, lA0);
    gload16(a1 + k0, lA1);
    gload16(b0 + k0, lB0);
    gload16(b1 + k0, lB1);
    asm volatile("s_waitcnt vmcnt(0)" ::: "memory");
    __syncthreads();
    bf16x8 af[4], bfr[4];
    #pragma unroll
    for (int i = 0; i < 4; i++)
      af[i] = *(const bf16x8*)(As + (wm * 64 + i * 16 + lr) * 32 + lk * 8);
    #pragma unroll
    for (int j = 0; j < 4; j++)
      bfr[j] = *(const bf16x8*)(Bs + (wn * 64 + j * 16 + lr) * 32 + lk * 8);
    #pragma unroll
    for (int i = 0; i < 4; i++)
      #pragma unroll
      for (int j = 0; j < 4; j++)
        acc[i][j] = __builtin_amdgcn_mfma_f32_16x16x32_bf16(af[i], bfr[j], acc[i][j], 0, 0, 0);
  }

  const int rb = (lane >> 4) * 4, cl = lane & 15;
  #pragma unroll
  for (int i = 0; i < 4; i++){
    #pragma unroll
    for (int j = 0; j < 4; j++){
      const int mb = m0 + wm * 64 + i * 16 + rb;
      const int n  = n0 + wn * 64 + j * 16 + cl;
      if (MODE == 7 && n >= 1024){           // V^T packed x4 along s
        int n1 = n - 1024, h = n1 >> 7, d = n1 & 127, b = mb >> 11, s = mb & 2047;
        u32 lo = (u32)f2b(acc[i][j][0]) | ((u32)f2b(acc[i][j][1]) << 16);
        u32 hi = (u32)f2b(acc[i][j][2]) | ((u32)f2b(acc[i][j][3]) << 16);
        *(uint2*)((u16*)D2 + (((size_t)(b * 16 + h) * 128 + d) * 2048 + s)) = make_uint2(lo, hi);
      } else {
        #pragma unroll
        for (int r = 0; r < 4; r++){
          int m = mb + r;
          float v = acc[i][j][r];
          if (MODE == 0){
            ((u16*)D)[(size_t)m * N + n] = f2b(v);
          } else if (MODE == 3){
            ((float*)D)[(size_t)m * N + n] = v;
          } else if (MODE == 6){
            if (n < 1024){
              ((u16*)D2)[(size_t)m * 1024 + n] = f2b(v);
            } else {
              int n1 = n - 1024, h = n1 >> 6, d = n1 & 63;
              ((u16*)D)[(((size_t)(m >> 11) * 16 + h) * 2048 + (m & 2047)) * 128 + d] = f2b(v);
            }
          } else if (MODE == 7){             // n < 1024 branch
            int h = n >> 6, d = n & 63;
            ((u16*)D)[(((size_t)(m >> 11) * 16 + h) * 2048 + (m & 2047)) * 128 + d] = f2b(v);
          }
        }
      }
    }
  }
}

// ---------------- RoPE: rotate q_r/k_r halves into q/k dims [64,128) ----------------
// qrp: (4096,1024) ld 1024; k_r lives inside dcat at col offset 512, ld 1536.
__global__ void rope_k(const u16* __restrict__ qrp, const u16* __restrict__ dcat,
                       u16* __restrict__ Qb, u16* __restrict__ Kb){
  int idx = blockIdx.x * 256 + threadIdx.x;         // 2*2048*16*32 = 2^21
  if (idx >= (1 << 21)) return;
  int j = idx & 31, h = (idx >> 5) & 15, s = (idx >> 9) & 2047, b = (idx >> 20) & 1;
  float inv = exp2f((float)j * (-13.287712379549449f / 32.0f));
  float ang = (float)s * inv;
  float sn = sinf(ang), cs = cosf(ang);
  size_t soq = ((size_t)(b * 2048 + s)) * 1024 + h * 64 + j;
  size_t sok = ((size_t)(b * 2048 + s)) * 1536 + 512 + h * 64 + j;
  size_t dd = (((size_t)(b * 16 + h)) * 2048 + s) * 128;
  {
    float x1 = b2f(qrp[soq]), x2 = b2f(qrp[soq + 32]);
    Qb[dd + 64 + j] = f2b(x1 * cs - x2 * sn);
    Qb[dd + 96 + j] = f2b(x1 * sn + x2 * cs);
  }
  {
    float x1 = b2f(dcat[sok]), x2 = b2f(dcat[sok + 32]);
    Kb[dd + 64 + j] = f2b(x1 * cs - x2 * sn);
    Kb[dd + 96 + j] = f2b(x1 * sn + x2 * cs);
  }
}

// ---------------- MFMA flash attention, diagonal-paired + double-buffered ----------------
// grid (32 bh, 8 pp); block: 4 waves x 32 q-rows = 128-row Q tile; processes q-tiles
// pp and 15-pp (uniform 34 k-tiles/block). K (B,NH,S,128); V^T (B,NH,128,S).
__global__ __launch_bounds__(256, 1)
void flash_mfma(const u16* __restrict__ Q, const u16* __restrict__ K,
                const u16* __restrict__ VT, u16* __restrict__ Y){
  __shared__ u16 k_s[2][8192];   // 64 x 128 per buf, swizzled
  __shared__ u16 v_s[2][8192];   // 128 x 64 per buf, swizzled
  __shared__ u16 p_s[4][2048];   // per-wave P / epilogue scratch
  const int tid = threadIdx.x;
  const int w = tid >> 6, l = tid & 63;
  const int lr = l & 15, hk = l >> 4, l7 = l & 7;
  const int bh = blockIdx.x, pp = blockIdx.y;
  const int b = bh >> 4, h = bh & 15;
  const size_t base = (size_t)bh * 2048 * 128;
  const u16* Qb = Q + base;
  const u16* Kb = K + base;
  const u16* Vb = VT + base;
  u16* myp = p_s[w];

  const int qtA = pp, qtB = 15 - pp;
  const int nktA = 2 * qtA + 2, nktB = 2 * qtB + 2;
  const int ntot = nktA + nktB;                 // always 34

  bf16x8 qa[2][4];
  f32x4 o[2][8];
  float mrow[2][4], lsum[2][4];
  int q0 = 0;

  auto initPhase = [&](int qt){
    q0 = qt * 128 + w * 32;
    #pragma unroll
    for (int mi = 0; mi < 2; ++mi){
      #pragma unroll
      for (int ks = 0; ks < 4; ++ks)
        qa[mi][ks] = *(const bf16x8*)(Qb + (size_t)(q0 + mi * 16 + lr) * 128 + ks * 32 + hk * 8);
      #pragma unroll
      for (int r = 0; r < 4; ++r){ mrow[mi][r] = -1e30f; lsum[mi][r] = 0.f; }
      #pragma unroll
      for (int dj = 0; dj < 8; ++dj) o[mi][dj] = f32x4{0.f, 0.f, 0.f, 0.f};
    }
  };

  auto STAGE = [&](int kt, int bb){
    #pragma unroll
    for (int it = 0; it < 4; ++it){
      int row = w * 16 + it * 4 + hk;
      gload16(Kb + (size_t)(kt * 64 + row) * 128 + (((lr ^ (row & 7)) << 3)),
              k_s[bb] + w * 2048 + it * 512);
    }
    #pragma unroll
    for (int it = 0; it < 4; ++it){
      int chunk = w * 4 + it;
      int d = chunk * 8 + (l >> 3);
      gload16(Vb + (size_t)d * 2048 + kt * 64 + ((l7 ^ (l >> 3)) << 3),
              v_s[bb] + chunk * 512);
    }
  };

  auto epilogue = [&](int qt){
    u16* scr = myp;                                  // 16 x 128 per chunk (4 KiB)
    #pragma unroll
    for (int mi = 0; mi < 2; ++mi){
      float inv[4];
      #pragma unroll
      for (int r = 0; r < 4; ++r) inv[r] = 1.0f / lsum[mi][r];
      #pragma unroll
      for (int dj = 0; dj < 8; ++dj)
        #pragma unroll
        for (int r = 0; r < 4; ++r)
          scr[(hk * 4 + r) * 128 + dj * 16 + lr] = f2b(o[mi][dj][r] * inv[r]);
      asm volatile("s_waitcnt lgkmcnt(0)" ::: "memory");
      #pragma unroll
      for (int rr = 0; rr < 4; ++rr){
        int row = rr * 4 + hk;
        uint4 vv = *(const uint4*)(scr + row * 128 + lr * 8);
        *(uint4*)(Y + ((size_t)(b * 2048) + qt * 128 + w * 32 + mi * 16 + row) * 2048
                      + h * 128 + lr * 8) = vv;
      }
      asm volatile("s_waitcnt lgkmcnt(0)" ::: "memory");  // reads done before overwrite
    }
  };

  initPhase(qtA);
  STAGE(0, 0);
  asm volatile("s_waitcnt vmcnt(0)" ::: "memory");
  __syncthreads();

  int bb = 0;
  for (int t = 0; t < ntot; ++t){
    const bool inA = (t < nktA);
    const int kt = inA ? t : t - nktA;
    if (t == nktA){ epilogue(qtA); initPhase(qtB); }
    if (t + 1 < ntot){
      int t2 = t + 1;
      STAGE((t2 < nktA) ? t2 : t2 - nktA, bb ^ 1);   // prefetch overlaps compute
    }

    if (kt * 64 <= q0 + 31){
      const u16* ks_ = k_s[bb];
      const u16* vs_ = v_s[bb];
      // ---- S = Q K^T ----
      f32x4 sc[2][4] = {};
      #pragma unroll
      for (int ks = 0; ks < 4; ++ks){
        bf16x8 kb[4];
        #pragma unroll
        for (int nj = 0; nj < 4; ++nj)
          kb[nj] = *(const bf16x8*)(ks_ + (nj * 16 + lr) * 128 + (((ks * 64 + hk * 16) ^ (l7 << 4)) >> 1));
        __builtin_amdgcn_s_setprio(1);
        #pragma unroll
        for (int mi = 0; mi < 2; ++mi)
          #pragma unroll
          for (int nj = 0; nj < 4; ++nj)
            sc[mi][nj] = __builtin_amdgcn_mfma_f32_16x16x32_bf16(qa[mi][ks], kb[nj], sc[mi][nj], 0, 0, 0);
        __builtin_amdgcn_s_setprio(0);
      }
      // ---- causal mask + online softmax (C layout: row=hk*4+r, col=lr) ----
      const float scale = 0.08838834764831845f;   // 1/sqrt(128)
      #pragma unroll
      for (int mi = 0; mi < 2; ++mi){
        #pragma unroll
        for (int r = 0; r < 4; ++r){
          int qrow = q0 + mi * 16 + hk * 4 + r;
          float pv[4], rmax = -1e30f;
          #pragma unroll
          for (int nj = 0; nj < 4; ++nj){
            int kc = kt * 64 + nj * 16 + lr;
            float s = (kc <= qrow) ? sc[mi][nj][r] * scale : -1e30f;
            pv[nj] = s; rmax = fmaxf(rmax, s);
          }
          #pragma unroll
          for (int off = 1; off < 16; off <<= 1) rmax = fmaxf(rmax, __shfl_xor(rmax, off));
          float mnew = fmaxf(mrow[mi][r], rmax);
          float alpha = __expf(mrow[mi][r] - mnew);
          mrow[mi][r] = mnew;
          int ql = mi * 16 + hk * 4 + r;
          int swz = (ql & 7) << 3;
          float rsum = 0.f;
          #pragma unroll
          for (int nj = 0; nj < 4; ++nj){
            float p = __expf(pv[nj] - mnew);
            rsum += p;
            myp[ql * 64 + ((nj * 16 + lr) ^ swz)] = f2b(p);
          }
          #pragma unroll
          for (int off = 1; off < 16; off <<= 1) rsum += __shfl_xor(rsum, off);
          lsum[mi][r] = lsum[mi][r] * alpha + rsum;
          #pragma unroll
          for (int dj = 0; dj < 8; ++dj) o[mi][dj][r] *= alpha;
        }
      }
      asm volatile("s_waitcnt lgkmcnt(0)" ::: "memory");   // P writes visible
      // ---- O += P V ----
      #pragma unroll
      for (int kk = 0; kk < 2; ++kk){
        bf16x8 pa[2], vb[8];
        #pragma unroll
        for (int mi = 0; mi < 2; ++mi)
          pa[mi] = *(const bf16x8*)(myp + (mi * 16 + lr) * 64 + ((kk * 32 + hk * 8) ^ (l7 << 3)));
        #pragma unroll
        for (int dj = 0; dj < 8; ++dj)
          vb[dj] = *(const bf16x8*)(vs_ + (dj * 16 + lr) * 64 + (((kk * 64 + hk * 16) ^ (l7 << 4)) >> 1));
        __builtin_amdgcn_s_setprio(1);
        #pragma unroll
        for (int mi = 0; mi < 2; ++mi)
          #pragma unroll
          for (int dj = 0; dj < 8; ++dj)
            o[mi][dj] = __builtin_amdgcn_mfma_f32_16x16x32_bf16(pa[mi], vb[dj], o[mi][dj], 0, 0, 0);
        __builtin_amdgcn_s_setprio(0);
      }
    }

    asm volatile("s_waitcnt vmcnt(0)" ::: "memory");   // prefetch landed
    __syncthreads();
    bb ^= 1;
  }
  epilogue(qtB);
}

// ---------------------------------------------------------------------------
extern "C" void kernel_launch(void* const* d_in, const int* in_sizes, int n_in,
                              void* d_out, int out_size, void* d_ws, size_t ws_size,
                              hipStream_t stream){
  u16* p = (u16*)d_ws;
  auto alloc = [&](size_t n){ u16* r = p; p += n; return r; };
  // contiguous bf16 weights: [W_kv_d | W_q_d | W_rope_k | W_rope_q | W_q_u | W_k_u | W_v_u | W_o]
  u16* wcat = alloc(8650752);
  u16* downW  = wcat;                 // 1536 x 2048
  u16* qcatW  = wcat + 3145728;       // 2048 x 256 (rope_q, q_u)
  u16* kvcatW = wcat + 3670016;       // 3072 x 256 (k_u, v_u)
  u16* wo     = wcat + 4456448;       // 2048 x 2048
  u16* xb   = alloc(8388608);         // (4096, 2048) bf16
  u16* dcat = alloc(6291456);         // (4096, 1536) = [kv_d | q_d | k_r_pre]
  u16* qrp  = alloc(4194304);         // (4096, 1024) q_r pre-rope
  u16* qbuf = alloc(8388608);         // (B,NH,S,128)
  u16* kbuf = alloc(8388608);
  u16* vt   = alloc(8388608);         // (B,NH,128,S)
  u16* ybuf = alloc(8388608);         // (4096, 2048)

  f2bf_k<<<8192, 256, 0, stream>>>((const float*)d_in[0], xb, 2097152);
  WSrc ws;
  ws.s[0] = (const float*)d_in[1];   // W_kv_d
  ws.s[1] = (const float*)d_in[2];   // W_q_d
  ws.s[2] = (const float*)d_in[6];   // W_rope_k
  ws.s[3] = (const float*)d_in[7];   // W_rope_q
  ws.s[4] = (const float*)d_in[4];   // W_q_u
  ws.s[5] = (const float*)d_in[3];   // W_k_u
  ws.s[6] = (const float*)d_in[5];   // W_v_u
  ws.s[7] = (const float*)d_in[8];   // W_o
  wcvt_k<<<8448, 256, 0, stream>>>(ws, wcat);

  dim3 blk(256);
  // down-projections fused: dcat = x @ [W_kv_d|W_q_d|W_rope_k]^T
  gemm_bt<0><<<dim3(12, 32), blk, 0, stream>>>(xb, 2048, downW, dcat, nullptr, 1536, 2048);
  // q-side up-projections fused: [q_r_pre -> qrp | q_c -> qbuf]
  gemm_bt<6><<<dim3(16, 32), blk, 0, stream>>>(dcat + 256, 1536, qcatW, qbuf, qrp, 2048, 256);
  // kv-side up-projections fused: [k_c -> kbuf | v -> vt (transposed)]
  gemm_bt<7><<<dim3(24, 32), blk, 0, stream>>>(dcat, 1536, kvcatW, kbuf, vt, 3072, 256);
  // rope into q/k dims [64,128)
  rope_k<<<(1 << 21) / 256, 256, 0, stream>>>(qrp, dcat, qbuf, kbuf);
  // attention (paired + double-buffered MFMA flash)
  flash_mfma<<<dim3(32, 8), blk, 0, stream>>>(qbuf, kbuf, vt, ybuf);
  // output projection (fp32 out)
  gemm_bt<3><<<dim3(16, 32), blk, 0, stream>>>(ybuf, 2048, wo, d_out, nullptr, 2048, 2048);
}

// Round 4
// 228.097 us; speedup vs baseline: 6.3339x; 1.3233x over previous
//
#include <hip/hip_runtime.h>

typedef unsigned short u16;
typedef unsigned int u32;
typedef __attribute__((ext_vector_type(8))) short bf16x8;
typedef __attribute__((ext_vector_type(4))) float f32x4;

#define DEVI static __device__ __forceinline__

DEVI u16 f2b(float f){
  u32 x = __float_as_uint(f);
  return (u16)((x + 0x7fffu + ((x >> 16) & 1u)) >> 16);   // RNE bf16
}
DEVI float b2f(u16 u){ return __uint_as_float(((u32)u) << 16); }
DEVI void gload16(const u16* g, u16* l){
  __builtin_amdgcn_global_load_lds((const __attribute__((address_space(1))) void*)g,
                                   (__attribute__((address_space(3))) void*)l,
                                   16, 0, 0);
}

// ---------------- fp32 -> bf16 convert: x (one launch) ----------------
__global__ void f2bf_k(const float* __restrict__ s, u16* __restrict__ d, int n4){
  int i = blockIdx.x * 256 + threadIdx.x;
  if (i >= n4) return;
  float4 f = ((const float4*)s)[i];
  u32 lo = (u32)f2b(f.x) | ((u32)f2b(f.y) << 16);
  u32 hi = (u32)f2b(f.z) | ((u32)f2b(f.w) << 16);
  ((uint2*)d)[i] = make_uint2(lo, hi);
}

// ---------------- all 8 weights -> one contiguous bf16 region ----------------
struct WSrc { const float* s[8]; };
__global__ void wcvt_k(WSrc ws, u16* __restrict__ d){
  int i = blockIdx.x * 256 + threadIdx.x;        // float4 index, total 2162688
  if (i >= 2162688) return;
  const float4* s; int lo;
  if      (i <  131072){ s = (const float4*)ws.s[0]; lo = 0;       }
  else if (i <  262144){ s = (const float4*)ws.s[1]; lo = 131072;  }
  else if (i <  786432){ s = (const float4*)ws.s[2]; lo = 262144;  }
  else if (i <  851968){ s = (const float4*)ws.s[3]; lo = 786432;  }
  else if (i <  917504){ s = (const float4*)ws.s[4]; lo = 851968;  }
  else if (i <  983040){ s = (const float4*)ws.s[5]; lo = 917504;  }
  else if (i < 1114112){ s = (const float4*)ws.s[6]; lo = 983040;  }
  else                 { s = (const float4*)ws.s[7]; lo = 1114112; }
  float4 f = s[i - lo];
  u32 a = (u32)f2b(f.x) | ((u32)f2b(f.y) << 16);
  u32 b = (u32)f2b(f.z) | ((u32)f2b(f.w) << 16);
  ((uint2*)d)[i] = make_uint2(a, b);
}

// ---------------- MFMA bf16 GEMM:  C[M,N] = A[M,K] * W[N,K]^T ----------------
template<int MODE>
__global__ __launch_bounds__(256, 2)
void gemm_bt(const u16* __restrict__ A, int lda, const u16* __restrict__ W,
             void* __restrict__ D, void* __restrict__ D2, int N, int K){
  __shared__ u16 As[128 * 32];
  __shared__ u16 Bs[128 * 32];
  const int tid = threadIdx.x;
  const int wave = tid >> 6, lane = tid & 63;
  const int lr = lane & 15, lk = lane >> 4;
  const int m0 = blockIdx.y * 128, n0 = blockIdx.x * 128;
  const int wm = wave >> 1, wn = wave & 1;
  f32x4 acc[4][4] = {};

  const u16* a0 = A + (size_t)(m0 + (tid >> 2)) * lda + (tid & 3) * 8;
  const u16* a1 = a0 + (size_t)64 * lda;
  const u16* b0 = W + (size_t)(n0 + (tid >> 2)) * K + (tid & 3) * 8;
  const u16* b1 = b0 + (size_t)64 * K;
  u16* lA0 = As + wave * 512;  u16* lA1 = As + 2048 + wave * 512;
  u16* lB0 = Bs + wave * 512;  u16* lB1 = Bs + 2048 + wave * 512;

  for (int k0 = 0; k0 < K; k0 += 32){
    __syncthreads();
    gload16(a0 + k0, lA0);
    gload16(a1 + k0, lA1);
    gload16(b0 + k0, lB0);
    gload16(b1 + k0, lB1);
    asm volatile("s_waitcnt vmcnt(0)" ::: "memory");
    __syncthreads();
    bf16x8 af[4], bfr[4];
    #pragma unroll
    for (int i = 0; i < 4; i++)
      af[i] = *(const bf16x8*)(As + (wm * 64 + i * 16 + lr) * 32 + lk * 8);
    #pragma unroll
    for (int j = 0; j < 4; j++)
      bfr[j] = *(const bf16x8*)(Bs + (wn * 64 + j * 16 + lr) * 32 + lk * 8);
    #pragma unroll
    for (int i = 0; i < 4; i++)
      #pragma unroll
      for (int j = 0; j < 4; j++)
        acc[i][j] = __builtin_amdgcn_mfma_f32_16x16x32_bf16(af[i], bfr[j], acc[i][j], 0, 0, 0);
  }

  const int rb = (lane >> 4) * 4, cl = lane & 15;
  #pragma unroll
  for (int i = 0; i < 4; i++){
    #pragma unroll
    for (int j = 0; j < 4; j++){
      const int mb = m0 + wm * 64 + i * 16 + rb;
      const int n  = n0 + wn * 64 + j * 16 + cl;
      if (MODE == 7 && n >= 1024){           // V^T packed x4 along s
        int n1 = n - 1024, h = n1 >> 7, d = n1 & 127, b = mb >> 11, s = mb & 2047;
        u32 lo = (u32)f2b(acc[i][j][0]) | ((u32)f2b(acc[i][j][1]) << 16);
        u32 hi = (u32)f2b(acc[i][j][2]) | ((u32)f2b(acc[i][j][3]) << 16);
        *(uint2*)((u16*)D2 + (((size_t)(b * 16 + h) * 128 + d) * 2048 + s)) = make_uint2(lo, hi);
      } else {
        #pragma unroll
        for (int r = 0; r < 4; r++){
          int m = mb + r;
          float v = acc[i][j][r];
          if (MODE == 0){
            ((u16*)D)[(size_t)m * N + n] = f2b(v);
          } else if (MODE == 3){
            ((float*)D)[(size_t)m * N + n] = v;
          } else if (MODE == 6){
            if (n < 1024){
              ((u16*)D2)[(size_t)m * 1024 + n] = f2b(v);
            } else {
              int n1 = n - 1024, h = n1 >> 6, d = n1 & 63;
              ((u16*)D)[(((size_t)(m >> 11) * 16 + h) * 2048 + (m & 2047)) * 128 + d] = f2b(v);
            }
          } else if (MODE == 7){             // n < 1024 branch
            int h = n >> 6, d = n & 63;
            ((u16*)D)[(((size_t)(m >> 11) * 16 + h) * 2048 + (m & 2047)) * 128 + d] = f2b(v);
          }
        }
      }
    }
  }
}

// ---------------- RoPE: rotate q_r/k_r halves into q/k dims [64,128) ----------------
__global__ void rope_k(const u16* __restrict__ qrp, const u16* __restrict__ dcat,
                       u16* __restrict__ Qb, u16* __restrict__ Kb){
  int idx = blockIdx.x * 256 + threadIdx.x;         // 2*2048*16*32 = 2^21
  if (idx >= (1 << 21)) return;
  int j = idx & 31, h = (idx >> 5) & 15, s = (idx >> 9) & 2047, b = (idx >> 20) & 1;
  float inv = exp2f((float)j * (-13.287712379549449f / 32.0f));
  float ang = (float)s * inv;
  float sn = sinf(ang), cs = cosf(ang);
  size_t soq = ((size_t)(b * 2048 + s)) * 1024 + h * 64 + j;
  size_t sok = ((size_t)(b * 2048 + s)) * 1536 + 512 + h * 64 + j;
  size_t dd = (((size_t)(b * 16 + h)) * 2048 + s) * 128;
  {
    float x1 = b2f(qrp[soq]), x2 = b2f(qrp[soq + 32]);
    Qb[dd + 64 + j] = f2b(x1 * cs - x2 * sn);
    Qb[dd + 96 + j] = f2b(x1 * sn + x2 * cs);
  }
  {
    float x1 = b2f(dcat[sok]), x2 = b2f(dcat[sok + 32]);
    Kb[dd + 64 + j] = f2b(x1 * cs - x2 * sn);
    Kb[dd + 96 + j] = f2b(x1 * sn + x2 * cs);
  }
}

// ---------------- MFMA flash attention: swapped-operand, lane-local softmax ----------------
// grid (32 bh, 16); qt = 15 - by (heavy first). 4 waves x 32 q-rows = 128-row Q tile.
// S^T = mfma(A=K, B=Q): lane holds P[q=lane&15][16 k] -> in-lane max, lane-local sum.
// O^T = mfma(A=V^T, B=P^T): q stays lane&15 -> alpha/normalize lane-local (T13 defer-max).
// LDS 64 KB: K dbuf 32K | V^T single 16K | P per-wave 16K  -> 2 blocks/CU.
__global__ __launch_bounds__(256, 2)
void flash_mfma(const u16* __restrict__ Q, const u16* __restrict__ K,
                const u16* __restrict__ VT, u16* __restrict__ Y){
  __shared__ u16 k_s[16384];     // 2 bufs x [64 k][128 d], rows 256 B, XOR-swizzled
  __shared__ u16 v_s[8192];      // [128 d][64 k], rows 128 B, XOR-swizzled
  __shared__ u16 p_s[8192];      // 4 waves x [32 q][64 k], rows 128 B, XOR-swizzled
  const int tid = threadIdx.x;
  const int w = tid >> 6, l = tid & 63;
  const int lr = l & 15, hk = l >> 4, l7 = l & 7;
  const int bh = blockIdx.x;
  const int qt = 15 - blockIdx.y;
  const int b = bh >> 4, h = bh & 15;
  const size_t base = (size_t)bh * 2048 * 128;
  const u16* Qb = Q + base;
  const u16* Kb = K + base;
  const u16* Vb = VT + base;
  u16* myp = p_s + w * 2048;
  const int q0 = qt * 128 + w * 32;
  const int nkt = 2 * qt + 2;

  // Q fragments: qa[mi][ks] = Q[q0+mi*16+lr][ks*32+hk*8 ..+8]  (A- and B-frag compatible)
  bf16x8 qa[2][4];
  #pragma unroll
  for (int mi = 0; mi < 2; mi++)
    #pragma unroll
    for (int ks = 0; ks < 4; ks++)
      qa[mi][ks] = *(const bf16x8*)(Qb + (size_t)(q0 + mi * 16 + lr) * 128 + ks * 32 + hk * 8);

  f32x4 o[2][8] = {};                 // o[mi][dj][r] = O^T[d=dj*16+hk*4+r][q=q0+mi*16+lr]
  float mbase[2] = {-1e30f, -1e30f};  // exp base per q-row (lane-local)
  float lsum[2] = {0.f, 0.f};         // lane-local partial denominator

  // prologue: stage K(0) into buf 0
  #pragma unroll
  for (int it = 0; it < 4; ++it){
    int row = w * 16 + it * 4 + hk;
    gload16(Kb + (size_t)row * 128 + ((lr ^ (row & 7)) << 3), k_s + w * 2048 + it * 512);
  }
  asm volatile("s_waitcnt vmcnt(0)" ::: "memory");
  __builtin_amdgcn_s_barrier();

  int bb = 0;
  for (int t = 0; t < nkt; ++t){
    // stage V(t) (single-buffered; prev PV done at entry barrier)
    #pragma unroll
    for (int it = 0; it < 4; ++it){
      int chunk = w * 4 + it;
      int d = chunk * 8 + (l >> 3);
      gload16(Vb + (size_t)d * 2048 + t * 64 + ((l7 ^ (l >> 3)) << 3), v_s + chunk * 512);
    }
    const bool pre = (t + 1 < nkt);
    if (pre){
      #pragma unroll
      for (int it = 0; it < 4; ++it){
        int row = w * 16 + it * 4 + hk;
        gload16(Kb + (size_t)((t + 1) * 64 + row) * 128 + ((lr ^ (row & 7)) << 3),
                k_s + (bb ^ 1) * 8192 + w * 2048 + it * 512);
      }
    }

    const bool act = (t * 64 <= q0 + 31);
    if (act){
      const u16* ks_ = k_s + bb * 8192;
      // ---- S^T = K Q^T ----
      f32x4 sc[2][4] = {};
      #pragma unroll
      for (int ksd = 0; ksd < 4; ++ksd){
        bf16x8 kb[4];
        #pragma unroll
        for (int nj = 0; nj < 4; ++nj){
          int row = nj * 16 + lr;
          kb[nj] = *(const bf16x8*)(ks_ + row * 128 + (((ksd * 64 + hk * 16) ^ ((row & 7) << 4)) >> 1));
        }
        __builtin_amdgcn_s_setprio(1);
        #pragma unroll
        for (int mi = 0; mi < 2; ++mi)
          #pragma unroll
          for (int nj = 0; nj < 4; ++nj)
            sc[mi][nj] = __builtin_amdgcn_mfma_f32_16x16x32_bf16(kb[nj], qa[mi][ksd], sc[mi][nj], 0, 0, 0);
        __builtin_amdgcn_s_setprio(0);
      }
      // ---- mask + scale + row-max (2 shfls per row) ----
      const float scale = 0.08838834764831845f;   // 1/sqrt(128)
      float pmax[2];
      #pragma unroll
      for (int mi = 0; mi < 2; ++mi){
        int qrow = q0 + mi * 16 + lr;
        float mx = -1e30f;
        #pragma unroll
        for (int nj = 0; nj < 4; ++nj)
          #pragma unroll
          for (int r = 0; r < 4; ++r){
            int kc = t * 64 + nj * 16 + hk * 4 + r;
            float s = (kc <= qrow) ? sc[mi][nj][r] * scale : -1e30f;
            sc[mi][nj][r] = s;
            mx = fmaxf(mx, s);
          }
        mx = fmaxf(mx, __shfl_xor(mx, 16));
        mx = fmaxf(mx, __shfl_xor(mx, 32));
        pmax[mi] = mx;
      }
      // ---- defer-max (T13): rescale only when base drifts >8 ----
      if (__any((pmax[0] > mbase[0] + 8.f) || (pmax[1] > mbase[1] + 8.f))){
        #pragma unroll
        for (int mi = 0; mi < 2; ++mi){
          float mnew = fmaxf(mbase[mi], pmax[mi]);
          float alpha = __expf(mbase[mi] - mnew);
          mbase[mi] = mnew;
          lsum[mi] *= alpha;
          #pragma unroll
          for (int dj = 0; dj < 8; ++dj)
            #pragma unroll
            for (int r = 0; r < 4; ++r) o[mi][dj][r] *= alpha;
        }
      }
      // ---- P = exp(S - base): lane-local sum, packed b64 LDS writes ----
      #pragma unroll
      for (int mi = 0; mi < 2; ++mi){
        const int qsw = (lr & 7) << 4;
        u16* prow = myp + (mi * 16 + lr) * 64;
        float rs = 0.f;
        #pragma unroll
        for (int nj = 0; nj < 4; ++nj){
          float p0 = __expf(sc[mi][nj][0] - mbase[mi]);
          float p1 = __expf(sc[mi][nj][1] - mbase[mi]);
          float p2 = __expf(sc[mi][nj][2] - mbase[mi]);
          float p3 = __expf(sc[mi][nj][3] - mbase[mi]);
          rs += (p0 + p1) + (p2 + p3);
          u32 a = (u32)f2b(p0) | ((u32)f2b(p1) << 16);
          u32 c = (u32)f2b(p2) | ((u32)f2b(p3) << 16);
          *(uint2*)(prow + (((nj * 32 + hk * 8) ^ qsw) >> 1)) = make_uint2(a, c);
        }
        lsum[mi] += rs;
      }
    }

    // ---- all waves: V landed (counted vmcnt keeps K-prefetch in flight, T4) ----
    if (pre) asm volatile("s_waitcnt vmcnt(4)" ::: "memory");
    else     asm volatile("s_waitcnt vmcnt(0)" ::: "memory");
    __builtin_amdgcn_s_barrier();
    asm volatile("s_waitcnt lgkmcnt(0)" ::: "memory");
    __builtin_amdgcn_sched_barrier(0);

    if (act){
      // ---- O^T += V^T P^T ----
      #pragma unroll
      for (int kk = 0; kk < 2; ++kk){
        bf16x8 pb[2], va[8];
        #pragma unroll
        for (int mi = 0; mi < 2; ++mi)
          pb[mi] = *(const bf16x8*)(myp + (mi * 16 + lr) * 64 + (((kk * 64 + hk * 16) ^ ((lr & 7) << 4)) >> 1));
        #pragma unroll
        for (int dj = 0; dj < 8; ++dj){
          int d = dj * 16 + lr;
          va[dj] = *(const bf16x8*)(v_s + d * 64 + (((kk * 64 + hk * 16) ^ ((lr & 7) << 4)) >> 1));
        }
        __builtin_amdgcn_s_setprio(1);
        #pragma unroll
        for (int mi = 0; mi < 2; ++mi)
          #pragma unroll
          for (int dj = 0; dj < 8; ++dj)
            o[mi][dj] = __builtin_amdgcn_mfma_f32_16x16x32_bf16(va[dj], pb[mi], o[mi][dj], 0, 0, 0);
        __builtin_amdgcn_s_setprio(0);
      }
    }

    asm volatile("s_waitcnt vmcnt(0)" ::: "memory");   // K(t+1) landed everywhere
    __builtin_amdgcn_s_barrier();
    bb ^= 1;
  }

  // ---- epilogue: lane-local l -> cross-hk reduce; transpose O^T via LDS; store ----
  u16* scr = k_s + w * 4096;            // 32 q x 128 d u16 per wave (8 KB)
  #pragma unroll
  for (int mi = 0; mi < 2; ++mi){
    float lt = lsum[mi];
    lt += __shfl_xor(lt, 16);
    lt += __shfl_xor(lt, 32);
    float inv = 1.0f / lt;
    const int q = mi * 16 + lr;
    const int qsw = (lr & 7) << 4;
    #pragma unroll
    for (int dj = 0; dj < 8; ++dj){
      u32 a = (u32)f2b(o[mi][dj][0] * inv) | ((u32)f2b(o[mi][dj][1] * inv) << 16);
      u32 c = (u32)f2b(o[mi][dj][2] * inv) | ((u32)f2b(o[mi][dj][3] * inv) << 16);
      *(uint2*)(scr + q * 128 + (((dj * 32 + hk * 8) ^ qsw) >> 1)) = make_uint2(a, c);
    }
  }
  asm volatile("s_waitcnt lgkmcnt(0)" ::: "memory");
  __builtin_amdgcn_sched_barrier(0);
  #pragma unroll
  for (int rr = 0; rr < 8; ++rr){
    int row = rr * 4 + hk;
    uint4 vv = *(const uint4*)(scr + row * 128 + (((lr * 16) ^ ((row & 7) << 4)) >> 1));
    *(uint4*)(Y + ((size_t)(b * 2048) + qt * 128 + w * 32 + row) * 2048 + h * 128 + lr * 8) = vv;
  }
}

// ---------------------------------------------------------------------------
extern "C" void kernel_launch(void* const* d_in, const int* in_sizes, int n_in,
                              void* d_out, int out_size, void* d_ws, size_t ws_size,
                              hipStream_t stream){
  u16* p = (u16*)d_ws;
  auto alloc = [&](size_t n){ u16* r = p; p += n; return r; };
  // contiguous bf16 weights: [W_kv_d | W_q_d | W_rope_k | W_rope_q | W_q_u | W_k_u | W_v_u | W_o]
  u16* wcat = alloc(8650752);
  u16* downW  = wcat;                 // 1536 x 2048
  u16* qcatW  = wcat + 3145728;       // 2048 x 256 (rope_q, q_u)
  u16* kvcatW = wcat + 3670016;       // 3072 x 256 (k_u, v_u)
  u16* wo     = wcat + 4456448;       // 2048 x 2048
  u16* xb   = alloc(8388608);         // (4096, 2048) bf16
  u16* dcat = alloc(6291456);         // (4096, 1536) = [kv_d | q_d | k_r_pre]
  u16* qrp  = alloc(4194304);         // (4096, 1024) q_r pre-rope
  u16* qbuf = alloc(8388608);         // (B,NH,S,128)
  u16* kbuf = alloc(8388608);
  u16* vt   = alloc(8388608);         // (B,NH,128,S)
  u16* ybuf = alloc(8388608);         // (4096, 2048)

  f2bf_k<<<8192, 256, 0, stream>>>((const float*)d_in[0], xb, 2097152);
  WSrc ws;
  ws.s[0] = (const float*)d_in[1];   // W_kv_d
  ws.s[1] = (const float*)d_in[2];   // W_q_d
  ws.s[2] = (const float*)d_in[6];   // W_rope_k
  ws.s[3] = (const float*)d_in[7];   // W_rope_q
  ws.s[4] = (const float*)d_in[4];   // W_q_u
  ws.s[5] = (const float*)d_in[3];   // W_k_u
  ws.s[6] = (const float*)d_in[5];   // W_v_u
  ws.s[7] = (const float*)d_in[8];   // W_o
  wcvt_k<<<8448, 256, 0, stream>>>(ws, wcat);

  dim3 blk(256);
  // down-projections fused: dcat = x @ [W_kv_d|W_q_d|W_rope_k]^T
  gemm_bt<0><<<dim3(12, 32), blk, 0, stream>>>(xb, 2048, downW, dcat, nullptr, 1536, 2048);
  // q-side up-projections fused: [q_r_pre -> qrp | q_c -> qbuf]
  gemm_bt<6><<<dim3(16, 32), blk, 0, stream>>>(dcat + 256, 1536, qcatW, qbuf, qrp, 2048, 256);
  // kv-side up-projections fused: [k_c -> kbuf | v -> vt (transposed)]
  gemm_bt<7><<<dim3(24, 32), blk, 0, stream>>>(dcat, 1536, kvcatW, kbuf, vt, 3072, 256);
  // rope into q/k dims [64,128)
  rope_k<<<(1 << 21) / 256, 256, 0, stream>>>(qrp, dcat, qbuf, kbuf);
  // attention (swapped-operand MFMA flash, heavy-first singles)
  flash_mfma<<<dim3(32, 16), blk, 0, stream>>>(qbuf, kbuf, vt, ybuf);
  // output projection (fp32 out)
  gemm_bt<3><<<dim3(16, 32), blk, 0, stream>>>(ybuf, 2048, wo, d_out, nullptr, 2048, 2048);
}

// Round 6
// 222.183 us; speedup vs baseline: 6.5025x; 1.0266x over previous
//
#include <hip/hip_runtime.h>

typedef unsigned short u16;
typedef unsigned int u32;
typedef __attribute__((ext_vector_type(8))) short bf16x8;
typedef __attribute__((ext_vector_type(4))) float f32x4;

#define DEVI static __device__ __forceinline__

DEVI u16 f2b(float f){
  u32 x = __float_as_uint(f);
  return (u16)((x + 0x7fffu + ((x >> 16) & 1u)) >> 16);   // RNE bf16
}
DEVI float b2f(u16 u){ return __uint_as_float(((u32)u) << 16); }
DEVI void gload16(const u16* g, u16* l){
  __builtin_amdgcn_global_load_lds((const __attribute__((address_space(1))) void*)g,
                                   (__attribute__((address_space(3))) void*)l,
                                   16, 0, 0);
}

// ---------------- fp32 -> bf16 convert: x (one launch) ----------------
__global__ void f2bf_k(const float* __restrict__ s, u16* __restrict__ d, int n4){
  int i = blockIdx.x * 256 + threadIdx.x;
  if (i >= n4) return;
  float4 f = ((const float4*)s)[i];
  u32 lo = (u32)f2b(f.x) | ((u32)f2b(f.y) << 16);
  u32 hi = (u32)f2b(f.z) | ((u32)f2b(f.w) << 16);
  ((uint2*)d)[i] = make_uint2(lo, hi);
}

// ---------------- all 8 weights -> one contiguous bf16 region ----------------
struct WSrc { const float* s[8]; };
__global__ void wcvt_k(WSrc ws, u16* __restrict__ d){
  int i = blockIdx.x * 256 + threadIdx.x;        // float4 index, total 2162688
  if (i >= 2162688) return;
  const float4* s; int lo;
  if      (i <  131072){ s = (const float4*)ws.s[0]; lo = 0;       }
  else if (i <  262144){ s = (const float4*)ws.s[1]; lo = 131072;  }
  else if (i <  786432){ s = (const float4*)ws.s[2]; lo = 262144;  }
  else if (i <  851968){ s = (const float4*)ws.s[3]; lo = 786432;  }
  else if (i <  917504){ s = (const float4*)ws.s[4]; lo = 851968;  }
  else if (i <  983040){ s = (const float4*)ws.s[5]; lo = 917504;  }
  else if (i < 1114112){ s = (const float4*)ws.s[6]; lo = 983040;  }
  else                 { s = (const float4*)ws.s[7]; lo = 1114112; }
  float4 f = s[i - lo];
  u32 a = (u32)f2b(f.x) | ((u32)f2b(f.y) << 16);
  u32 b = (u32)f2b(f.z) | ((u32)f2b(f.w) << 16);
  ((uint2*)d)[i] = make_uint2(a, b);
}

// ---------------- MFMA bf16 GEMM:  C[M,N] = A[M,K] * W[N,K]^T ----------------
template<int MODE>
__global__ __launch_bounds__(256, 2)
void gemm_bt(const u16* __restrict__ A, int lda, const u16* __restrict__ W,
             void* __restrict__ D, void* __restrict__ D2, int N, int K){
  __shared__ u16 As[128 * 32];
  __shared__ u16 Bs[128 * 32];
  const int tid = threadIdx.x;
  const int wave = tid >> 6, lane = tid & 63;
  const int lr = lane & 15, lk = lane >> 4;
  const int m0 = blockIdx.y * 128, n0 = blockIdx.x * 128;
  const int wm = wave >> 1, wn = wave & 1;
  f32x4 acc[4][4] = {};

  const u16* a0 = A + (size_t)(m0 + (tid >> 2)) * lda + (tid & 3) * 8;
  const u16* a1 = a0 + (size_t)64 * lda;
  const u16* b0 = W + (size_t)(n0 + (tid >> 2)) * K + (tid & 3) * 8;
  const u16* b1 = b0 + (size_t)64 * K;
  u16* lA0 = As + wave * 512;  u16* lA1 = As + 2048 + wave * 512;
  u16* lB0 = Bs + wave * 512;  u16* lB1 = Bs + 2048 + wave * 512;

  for (int k0 = 0; k0 < K; k0 += 32){
    __syncthreads();
    gload16(a0 + k0, lA0);
    gload16(a1 + k0, lA1);
    gload16(b0 + k0, lB0);
    gload16(b1 + k0, lB1);
    asm volatile("s_waitcnt vmcnt(0)" ::: "memory");
    __syncthreads();
    bf16x8 af[4], bfr[4];
    #pragma unroll
    for (int i = 0; i < 4; i++)
      af[i] = *(const bf16x8*)(As + (wm * 64 + i * 16 + lr) * 32 + lk * 8);
    #pragma unroll
    for (int j = 0; j < 4; j++)
      bfr[j] = *(const bf16x8*)(Bs + (wn * 64 + j * 16 + lr) * 32 + lk * 8);
    #pragma unroll
    for (int i = 0; i < 4; i++)
      #pragma unroll
      for (int j = 0; j < 4; j++)
        acc[i][j] = __builtin_amdgcn_mfma_f32_16x16x32_bf16(af[i], bfr[j], acc[i][j], 0, 0, 0);
  }

  const int rb = (lane >> 4) * 4, cl = lane & 15;
  const float qscale = 0.08838834764831845f;   // 1/sqrt(128): pre-scale q_c
  #pragma unroll
  for (int i = 0; i < 4; i++){
    #pragma unroll
    for (int j = 0; j < 4; j++){
      const int mb = m0 + wm * 64 + i * 16 + rb;
      const int n  = n0 + wn * 64 + j * 16 + cl;
      if (MODE == 7 && n >= 1024){           // V^T packed x4 along s
        int n1 = n - 1024, h = n1 >> 7, d = n1 & 127, b = mb >> 11, s = mb & 2047;
        u32 lo = (u32)f2b(acc[i][j][0]) | ((u32)f2b(acc[i][j][1]) << 16);
        u32 hi = (u32)f2b(acc[i][j][2]) | ((u32)f2b(acc[i][j][3]) << 16);
        *(uint2*)((u16*)D2 + (((size_t)(b * 16 + h) * 128 + d) * 2048 + s)) = make_uint2(lo, hi);
      } else {
        #pragma unroll
        for (int r = 0; r < 4; r++){
          int m = mb + r;
          float v = acc[i][j][r];
          if (MODE == 0){
            ((u16*)D)[(size_t)m * N + n] = f2b(v);
          } else if (MODE == 3){
            ((float*)D)[(size_t)m * N + n] = v;
          } else if (MODE == 6){
            if (n < 1024){
              ((u16*)D2)[(size_t)m * 1024 + n] = f2b(v);
            } else {
              int n1 = n - 1024, h = n1 >> 6, d = n1 & 63;
              ((u16*)D)[(((size_t)(m >> 11) * 16 + h) * 2048 + (m & 2047)) * 128 + d] = f2b(v * qscale);
            }
          } else if (MODE == 7){             // n < 1024 branch
            int h = n >> 6, d = n & 63;
            ((u16*)D)[(((size_t)(m >> 11) * 16 + h) * 2048 + (m & 2047)) * 128 + d] = f2b(v);
          }
        }
      }
    }
  }
}

// ---------------- RoPE: rotate q_r/k_r halves into q/k dims [64,128) ----------------
__global__ void rope_k(const u16* __restrict__ qrp, const u16* __restrict__ dcat,
                       u16* __restrict__ Qb, u16* __restrict__ Kb){
  int idx = blockIdx.x * 256 + threadIdx.x;         // 2*2048*16*32 = 2^21
  if (idx >= (1 << 21)) return;
  int j = idx & 31, h = (idx >> 5) & 15, s = (idx >> 9) & 2047, b = (idx >> 20) & 1;
  float inv = exp2f((float)j * (-13.287712379549449f / 32.0f));
  float ang = (float)s * inv;
  float sn = sinf(ang), cs = cosf(ang);
  const float qscale = 0.08838834764831845f;        // 1/sqrt(128): pre-scale q_r
  size_t soq = ((size_t)(b * 2048 + s)) * 1024 + h * 64 + j;
  size_t sok = ((size_t)(b * 2048 + s)) * 1536 + 512 + h * 64 + j;
  size_t dd = (((size_t)(b * 16 + h)) * 2048 + s) * 128;
  {
    float x1 = b2f(qrp[soq]), x2 = b2f(qrp[soq + 32]);
    Qb[dd + 64 + j] = f2b((x1 * cs - x2 * sn) * qscale);
    Qb[dd + 96 + j] = f2b((x1 * sn + x2 * cs) * qscale);
  }
  {
    float x1 = b2f(dcat[sok]), x2 = b2f(dcat[sok + 32]);
    Kb[dd + 64 + j] = f2b(x1 * cs - x2 * sn);
    Kb[dd + 96 + j] = f2b(x1 * sn + x2 * cs);
  }
}

// ---------------- MFMA flash attention v3b: KVBLK=128, swapped operands ----------------
// grid (32 bh, 16); qt = 15 - by (heavy first). 4 waves x 32 q-rows = 128-row Q tile.
// S^T = mfma(A=K, B=Q): lane holds P^T[k][q=lane&15]; lane-local softmax.
// O^T = mfma(A=V^T, B=P^T). LDS 128 KB: K dbuf 64K | V 32K | P 32K.
// vs R5: cvt_pk asm -> f2b pairs; defer-max -> unconditional 2-shuffle rescale (bisect).
__global__ __launch_bounds__(256, 1)
void flash_mfma(const u16* __restrict__ Q, const u16* __restrict__ K,
                const u16* __restrict__ VT, u16* __restrict__ Y){
  __shared__ u16 k_s[2][16384];  // [128 k][128 d] per buf, 256B rows, 4-bit XOR swizzle
  __shared__ u16 v_s[16384];     // [128 d][128 k], 256B rows, 4-bit XOR swizzle
  __shared__ u16 p_s[4][4096];   // per-wave [32 q][128 k], 256B rows, swizzled
  const int tid = threadIdx.x;
  const int w = tid >> 6, l = tid & 63;
  const int lr = l & 15, hk = l >> 4;
  const int bh = blockIdx.x;
  const int qt = 15 - blockIdx.y;
  const int b = bh >> 4, h = bh & 15;
  const size_t base = (size_t)bh * 2048 * 128;
  const u16* Qb = Q + base;
  const u16* Kb = K + base;
  const u16* Vb = VT + base;
  u16* myp = p_s[w];
  const int q0 = qt * 128 + w * 32;
  const int nkt = qt + 1;
  const int sr = w * 4 + hk;            // staging row-within-16 (= tid>>4)

  // Q fragments (pre-scaled by 1/sqrt(128) upstream); A- and B-frag compatible.
  bf16x8 qa[2][4];
  #pragma unroll
  for (int mi = 0; mi < 2; mi++)
    #pragma unroll
    for (int ks = 0; ks < 4; ks++)
      qa[mi][ks] = *(const bf16x8*)(Qb + (size_t)(q0 + mi * 16 + lr) * 128 + ks * 32 + hk * 8);

  f32x4 o[2][8] = {};                 // o[mi][dj][r] = O^T[d=dj*16+hk*4+r][q=q0+mi*16+lr]
  float mbase[2] = {-1e30f, -1e30f};
  float lsum[2] = {0.f, 0.f};

  auto STAGE_K = [&](int kt, int bb){
    #pragma unroll
    for (int it = 0; it < 8; ++it){
      int row = it * 16 + sr;
      gload16(Kb + (size_t)(kt * 128 + row) * 128 + ((lr ^ (row & 15)) << 3),
              &k_s[bb][it * 2048 + w * 512]);
    }
  };
  auto STAGE_V = [&](int kt){
    #pragma unroll
    for (int it = 0; it < 8; ++it){
      int d = it * 16 + sr;
      gload16(Vb + (size_t)d * 2048 + kt * 128 + ((lr ^ (d & 15)) << 3),
              &v_s[it * 2048 + w * 512]);
    }
  };

  // prologue: K(0) -> buf 0
  STAGE_K(0, 0);
  asm volatile("s_waitcnt vmcnt(0)" ::: "memory");
  __builtin_amdgcn_s_barrier();

  int bb = 0;
  for (int t = 0; t < nkt; ++t){
    STAGE_V(t);                          // 8 loads
    const bool pre = (t + 1 < nkt);
    if (pre) STAGE_K(t + 1, bb ^ 1);     // 8 more loads

    // ---- S^T = K Q^T (128 k-rows x 32 q-cols per wave) ----
    const u16* ks_ = k_s[bb];
    f32x4 sc[2][8] = {};
    #pragma unroll
    for (int ksd = 0; ksd < 4; ++ksd){
      bf16x8 kb[8];
      #pragma unroll
      for (int nj = 0; nj < 8; ++nj)
        kb[nj] = *(const bf16x8*)(ks_ + (nj * 16 + lr) * 128 + (((ksd * 64 + hk * 16) ^ (lr << 4)) >> 1));
      __builtin_amdgcn_s_setprio(1);
      #pragma unroll
      for (int mi = 0; mi < 2; ++mi)
        #pragma unroll
        for (int nj = 0; nj < 8; ++nj)
          sc[mi][nj] = __builtin_amdgcn_mfma_f32_16x16x32_bf16(kb[nj], qa[mi][ksd], sc[mi][nj], 0, 0, 0);
      __builtin_amdgcn_s_setprio(0);
    }

    // ---- mask (diagonal tile only) + lane-local max ----
    float lmax[2] = {-3e38f, -3e38f};
    if (t == qt){
      #pragma unroll
      for (int mi = 0; mi < 2; ++mi){
        int qrow = q0 + mi * 16 + lr;
        #pragma unroll
        for (int nj = 0; nj < 8; ++nj)
          #pragma unroll
          for (int r = 0; r < 4; ++r){
            int kc = t * 128 + nj * 16 + hk * 4 + r;
            float s = (kc <= qrow) ? sc[mi][nj][r] : -1e30f;
            sc[mi][nj][r] = s;
            lmax[mi] = fmaxf(lmax[mi], s);
          }
      }
    } else {
      #pragma unroll
      for (int mi = 0; mi < 2; ++mi)
        #pragma unroll
        for (int nj = 0; nj < 8; ++nj)
          #pragma unroll
          for (int r = 0; r < 4; ++r)
            lmax[mi] = fmaxf(lmax[mi], sc[mi][nj][r]);
    }

    // ---- unconditional online rescale (R4-proven path; 2 shuffles per mi) ----
    #pragma unroll
    for (int mi = 0; mi < 2; ++mi){
      float mx = lmax[mi];
      mx = fmaxf(mx, __shfl_xor(mx, 16));
      mx = fmaxf(mx, __shfl_xor(mx, 32));
      float mnew = fmaxf(mbase[mi], mx);
      float alpha = __expf(mbase[mi] - mnew);
      mbase[mi] = mnew;
      lsum[mi] *= alpha;
      #pragma unroll
      for (int dj = 0; dj < 8; ++dj)
        #pragma unroll
        for (int r = 0; r < 4; ++r) o[mi][dj][r] *= alpha;
    }

    // ---- P = exp(S - base): lane-local sum, packed writes (f2b pairs) ----
    #pragma unroll
    for (int mi = 0; mi < 2; ++mi){
      u16* prow = myp + (mi * 16 + lr) * 128;
      float rs = 0.f;
      #pragma unroll
      for (int nj = 0; nj < 8; ++nj){
        float p0 = __expf(sc[mi][nj][0] - mbase[mi]);
        float p1 = __expf(sc[mi][nj][1] - mbase[mi]);
        float p2 = __expf(sc[mi][nj][2] - mbase[mi]);
        float p3 = __expf(sc[mi][nj][3] - mbase[mi]);
        rs += (p0 + p1) + (p2 + p3);
        u32 a = (u32)f2b(p0) | ((u32)f2b(p1) << 16);
        u32 c = (u32)f2b(p2) | ((u32)f2b(p3) << 16);
        *(uint2*)(prow + (((nj * 32 + hk * 8) ^ (lr << 4)) >> 1)) = make_uint2(a, c);
      }
      lsum[mi] += rs;
    }

    // ---- V landed (counted: K prefetch stays in flight, T4) ----
    if (pre) asm volatile("s_waitcnt vmcnt(8)" ::: "memory");
    else     asm volatile("s_waitcnt vmcnt(0)" ::: "memory");
    __builtin_amdgcn_s_barrier();
    asm volatile("s_waitcnt lgkmcnt(0)" ::: "memory");   // own P writes visible
    __builtin_amdgcn_sched_barrier(0);

    // ---- O^T += V^T P^T ----
    #pragma unroll
    for (int kk = 0; kk < 4; ++kk){
      bf16x8 pb[2], va[8];
      #pragma unroll
      for (int mi = 0; mi < 2; ++mi)
        pb[mi] = *(const bf16x8*)(myp + (mi * 16 + lr) * 128 + (((kk * 64 + hk * 16) ^ (lr << 4)) >> 1));
      #pragma unroll
      for (int dj = 0; dj < 8; ++dj)
        va[dj] = *(const bf16x8*)(&v_s[(dj * 16 + lr) * 128 + (((kk * 64 + hk * 16) ^ (lr << 4)) >> 1)]);
      __builtin_amdgcn_s_setprio(1);
      #pragma unroll
      for (int mi = 0; mi < 2; ++mi)
        #pragma unroll
        for (int dj = 0; dj < 8; ++dj)
          o[mi][dj] = __builtin_amdgcn_mfma_f32_16x16x32_bf16(va[dj], pb[mi], o[mi][dj], 0, 0, 0);
      __builtin_amdgcn_s_setprio(0);
    }

    asm volatile("s_waitcnt vmcnt(0)" ::: "memory");   // K(t+1) landed everywhere
    __builtin_amdgcn_s_barrier();
    bb ^= 1;
  }

  // ---- epilogue: reduce l across hk; transpose O^T via LDS; coalesced store ----
  u16* scr = &k_s[0][0] + w * 4096;     // 32 q x 128 d per wave
  #pragma unroll
  for (int mi = 0; mi < 2; ++mi){
    float lt = lsum[mi];
    lt += __shfl_xor(lt, 16);
    lt += __shfl_xor(lt, 32);
    float inv = 1.0f / lt;
    const int q = mi * 16 + lr;
    const int qsw = (lr & 7) << 4;
    #pragma unroll
    for (int dj = 0; dj < 8; ++dj){
      u32 a = (u32)f2b(o[mi][dj][0] * inv) | ((u32)f2b(o[mi][dj][1] * inv) << 16);
      u32 c = (u32)f2b(o[mi][dj][2] * inv) | ((u32)f2b(o[mi][dj][3] * inv) << 16);
      *(uint2*)(scr + q * 128 + (((dj * 32 + hk * 8) ^ qsw) >> 1)) = make_uint2(a, c);
    }
  }
  asm volatile("s_waitcnt lgkmcnt(0)" ::: "memory");
  __builtin_amdgcn_sched_barrier(0);
  #pragma unroll
  for (int rr = 0; rr < 8; ++rr){
    int row = rr * 4 + hk;
    uint4 vv = *(const uint4*)(scr + row * 128 + (((lr * 16) ^ ((row & 7) << 4)) >> 1));
    *(uint4*)(Y + ((size_t)(b * 2048) + qt * 128 + w * 32 + row) * 2048 + h * 128 + lr * 8) = vv;
  }
}

// ---------------------------------------------------------------------------
extern "C" void kernel_launch(void* const* d_in, const int* in_sizes, int n_in,
                              void* d_out, int out_size, void* d_ws, size_t ws_size,
                              hipStream_t stream){
  u16* p = (u16*)d_ws;
  auto alloc = [&](size_t n){ u16* r = p; p += n; return r; };
  // contiguous bf16 weights: [W_kv_d | W_q_d | W_rope_k | W_rope_q | W_q_u | W_k_u | W_v_u | W_o]
  u16* wcat = alloc(8650752);
  u16* downW  = wcat;                 // 1536 x 2048
  u16* qcatW  = wcat + 3145728;       // 2048 x 256 (rope_q, q_u)
  u16* kvcatW = wcat + 3670016;       // 3072 x 256 (k_u, v_u)
  u16* wo     = wcat + 4456448;       // 2048 x 2048
  u16* xb   = alloc(8388608);         // (4096, 2048) bf16
  u16* dcat = alloc(6291456);         // (4096, 1536) = [kv_d | q_d | k_r_pre]
  u16* qrp  = alloc(4194304);         // (4096, 1024) q_r pre-rope
  u16* qbuf = alloc(8388608);         // (B,NH,S,128)
  u16* kbuf = alloc(8388608);
  u16* vt   = alloc(8388608);         // (B,NH,128,S)
  u16* ybuf = alloc(8388608);         // (4096, 2048)

  f2bf_k<<<8192, 256, 0, stream>>>((const float*)d_in[0], xb, 2097152);
  WSrc ws;
  ws.s[0] = (const float*)d_in[1];   // W_kv_d
  ws.s[1] = (const float*)d_in[2];   // W_q_d
  ws.s[2] = (const float*)d_in[6];   // W_rope_k
  ws.s[3] = (const float*)d_in[7];   // W_rope_q
  ws.s[4] = (const float*)d_in[4];   // W_q_u
  ws.s[5] = (const float*)d_in[3];   // W_k_u
  ws.s[6] = (const float*)d_in[5];   // W_v_u
  ws.s[7] = (const float*)d_in[8];   // W_o
  wcvt_k<<<8448, 256, 0, stream>>>(ws, wcat);

  dim3 blk(256);
  // down-projections fused: dcat = x @ [W_kv_d|W_q_d|W_rope_k]^T
  gemm_bt<0><<<dim3(12, 32), blk, 0, stream>>>(xb, 2048, downW, dcat, nullptr, 1536, 2048);
  // q-side up-projections fused: [q_r_pre -> qrp | q_c -> qbuf (pre-scaled)]
  gemm_bt<6><<<dim3(16, 32), blk, 0, stream>>>(dcat + 256, 1536, qcatW, qbuf, qrp, 2048, 256);
  // kv-side up-projections fused: [k_c -> kbuf | v -> vt (transposed)]
  gemm_bt<7><<<dim3(24, 32), blk, 0, stream>>>(dcat, 1536, kvcatW, kbuf, vt, 3072, 256);
  // rope into q/k dims [64,128) (q pre-scaled)
  rope_k<<<(1 << 21) / 256, 256, 0, stream>>>(qrp, dcat, qbuf, kbuf);
  // attention (KVBLK=128 swapped-operand MFMA flash, heavy-first)
  flash_mfma<<<dim3(32, 16), blk, 0, stream>>>(qbuf, kbuf, vt, ybuf);
  // output projection (fp32 out)
  gemm_bt<3><<<dim3(16, 32), blk, 0, stream>>>(ybuf, 2048, wo, d_out, nullptr, 2048, 2048);
}